// Round 8
// baseline (881.205 us; speedup 1.0000x reference)
//
#include <hip/hip_runtime.h>
#include <hip/hip_bf16.h>

typedef __hip_bfloat16 bf16;
typedef __attribute__((ext_vector_type(8))) short bf16x8;
typedef __attribute__((ext_vector_type(4))) float f32x4;

#define NN 30000      // nodes
#define NE 240000     // edges
#define NG 1500       // graphs
#define EMB 300
#define HID 600
#define NTASK 12
#define SEM 320       // padded stride for EMB-dim tensors
#define SHID 608      // padded stride for HID-dim tensors
#define CG 75         // 4-channel groups — 75 thr/node: best TLP (round-9 lesson)
#define NBLK_SCAN 118 // (NN+255)/256
#define MS 15104      // row split for l3/l4 GEMM pipeline (118 row-blocks)

__device__ __forceinline__ float tof(bf16 v){ return __bfloat162float(v); }
__device__ __forceinline__ bf16  tob(float v){ return __float2bfloat16(v); }
__device__ __forceinline__ float b2f(unsigned short u){ return __uint_as_float(((unsigned)u)<<16); }

// bijective XCD-aware block swizzle (m204): dispatch slot orig lands on XCD orig%8 (RR);
// give each XCD a CONTIGUOUS tile range so column-tiles sharing an A row-panel hit one L2.
__device__ __forceinline__ int xcd_swz(int orig, int nwg){
    int q = nwg >> 3, r = nwg & 7;
    int x = orig & 7, w = orig >> 3;
    return (x < r ? x*(q+1) : r*(q+1) + (x-r)*q) + w;
}

// ---------------- CSR build (by dst) ----------------
__global__ __launch_bounds__(256) void k_hist(const int* __restrict__ dst, int* __restrict__ deg){
    int e = blockIdx.x*256 + threadIdx.x;
    if (e < NE) atomicAdd(&deg[dst[e]], 1);
}

__global__ __launch_bounds__(256) void k_scanA(const int* __restrict__ deg, int* __restrict__ bsum){
    __shared__ int red[256];
    int b = blockIdx.x, t = threadIdx.x;
    int i = b*256 + t;
    red[t] = (i < NN) ? deg[i] : 0;
    __syncthreads();
    for (int off=128; off>0; off>>=1){ if (t<off) red[t]+=red[t+off]; __syncthreads(); }
    if (t==0) bsum[b] = red[0];
}

__global__ __launch_bounds__(128) void k_scanB(const int* __restrict__ bsum, int* __restrict__ boff){
    __shared__ int s[128];
    int t = threadIdx.x;
    int v = (t < NBLK_SCAN) ? bsum[t] : 0;
    s[t] = v;
    __syncthreads();
    for (int off=1; off<128; off<<=1){
        int add = (t>=off) ? s[t-off] : 0;
        __syncthreads();
        s[t] += add;
        __syncthreads();
    }
    if (t < NBLK_SCAN) boff[t] = s[t] - v;   // exclusive
}

__global__ __launch_bounds__(256) void k_scanC(const int* __restrict__ deg, const int* __restrict__ boff,
                                               int* __restrict__ indptr, int* __restrict__ cursor){
    __shared__ int s[256];
    int b = blockIdx.x, t = threadIdx.x;
    int i = b*256 + t;
    int v = (i < NN) ? deg[i] : 0;
    s[t] = v;
    __syncthreads();
    for (int off=1; off<256; off<<=1){
        int add = (t>=off) ? s[t-off] : 0;
        __syncthreads();
        s[t] += add;
        __syncthreads();
    }
    int excl = s[t] - v + boff[b];
    if (i < NN){ indptr[i] = excl; cursor[i] = excl; }
    if (i == 0) indptr[NN] = NE;
}

// scatter + edge pack fused: write epack directly at the atomic cursor slot (no eid pass)
__global__ __launch_bounds__(256) void k_scatterprep(const int* __restrict__ dst, const int* __restrict__ src,
                      const float* __restrict__ eattr, int* __restrict__ cursor, float4* __restrict__ epack){
    int e = blockIdx.x*256 + threadIdx.x;
    if (e >= NE) return;
    int p = atomicAdd(&cursor[dst[e]], 1);
    float4 q;
    q.x = __int_as_float(src[e]);
    q.y = eattr[e*3]; q.z = eattr[e*3+1]; q.w = eattr[e*3+2];
    epack[p] = q;
}

// ---------------- batched preamble: weight transposes + zeros + gstart + node encoder ----------------
// z: 0..4 W1_g | 5..9 W2_g | 10..11 W1_r | 12..13 W2_r | 14 Wg1 | 15 Wp1 | 16 zero deg+glogit | 17 gstart
// z >= 18: node encoder slices
__global__ __launch_bounds__(256) void k_wprep_all(
        const float* __restrict__ W1_g, const float* __restrict__ W2_g,
        const float* __restrict__ W1_r, const float* __restrict__ W2_r,
        const float* __restrict__ Wg1,  const float* __restrict__ Wp1,
        bf16* __restrict__ wt1g, bf16* __restrict__ wt2g,
        bf16* __restrict__ wt1r, bf16* __restrict__ wt2r,
        bf16* __restrict__ wtg1, bf16* __restrict__ wtp1,
        int* __restrict__ deg, const int* __restrict__ batch, int* __restrict__ gstart,
        const float* __restrict__ x, const float* __restrict__ W_enc,
        const float* __restrict__ b_enc, bf16* __restrict__ xfeat,
        float* __restrict__ glogit){
    __shared__ float t[32][33];
    int z = blockIdx.z;
    if (z >= 18){
        int idx = ((z-18)*361 + blockIdx.y*19 + blockIdx.x)*256 + threadIdx.x;
        if (idx >= NN*EMB) return;
        int n = idx / EMB, c = idx - n*EMB;
        float acc = b_enc[c];
        #pragma unroll
        for (int k=0;k<9;k++) acc += x[n*9+k] * W_enc[k*EMB+c];
        xfeat[(size_t)n*SEM + c] = tob(acc);
        return;
    }
    if (z == 16){
        int i = (blockIdx.y*19 + blockIdx.x)*256 + threadIdx.x;
        if (i < NN){ deg[i] = 0; glogit[2*i] = 0.f; glogit[2*i+1] = 0.f; }
        return;
    }
    if (z == 17){
        int g = (blockIdx.y*19 + blockIdx.x)*256 + threadIdx.x;
        if (g > NG) return;
        if (g == NG){ gstart[NG] = NN; return; }
        int lo=0, hi=NN;
        while (lo<hi){ int mid=(lo+hi)>>1; if (batch[mid] < g) lo=mid+1; else hi=mid; }
        gstart[g] = lo;
        return;
    }
    const float* Ws; bf16* Wd; int K, Kp, N;
    if (z < 5)      { Ws = W1_g + (size_t)z*EMB*HID;      Wd = wt1g + (size_t)z*HID*SEM;      K=EMB; Kp=SEM;  N=HID; }
    else if (z < 10){ int l=z-5;  Ws = W2_g + (size_t)l*HID*EMB; Wd = wt2g + (size_t)l*EMB*SHID; K=HID; Kp=SHID; N=EMB; }
    else if (z < 12){ int l=z-10; Ws = W1_r + (size_t)l*EMB*HID; Wd = wt1r + (size_t)l*HID*SEM;  K=EMB; Kp=SEM;  N=HID; }
    else if (z < 14){ int l=z-12; Ws = W2_r + (size_t)l*HID*EMB; Wd = wt2r + (size_t)l*EMB*SHID; K=HID; Kp=SHID; N=EMB; }
    else if (z ==14){ Ws = Wg1; Wd = wtg1; K=EMB; Kp=SEM; N=HID; }
    else            { Ws = Wp1; Wd = wtp1; K=EMB; Kp=SEM; N=HID; }
    int n0 = blockIdx.x*32, k0 = blockIdx.y*32;
    if (n0 >= N || k0 >= Kp) return;
    int tx = threadIdx.x & 31, ty = threadIdx.x >> 5;
    #pragma unroll
    for (int i=0;i<4;i++){
        int k = k0 + ty + i*8, n = n0 + tx;
        t[ty+i*8][tx] = (k<K && n<N) ? Ws[(size_t)k*N+n] : 0.f;
    }
    __syncthreads();
    #pragma unroll
    for (int i=0;i<4;i++){
        int n = n0 + ty + i*8, k = k0 + tx;
        if (n<N && k<Kp) Wd[(size_t)n*Kp+k] = tob(t[tx][ty+i*8]);
    }
}

// ---------------- agg body (device): thread=(node, 4-ch group), 2-deep pipeline ----------------
__device__ __forceinline__ void agg4_body(const bf16* __restrict__ cur, const float* __restrict__ We,
                      const float* __restrict__ be, const float4* __restrict__ epack,
                      const int* __restrict__ indptr, bf16* __restrict__ apx, int idx){
    int n = idx / CG, cg = idx - n*CG;
    int c0 = cg*4;
    float w0[4], w1[4], w2[4], bbv[4], acc[4];
    #pragma unroll
    for (int j=0;j<4;j++){
        w0[j] = We[c0+j]; w1[j] = We[EMB+c0+j]; w2[j] = We[2*EMB+c0+j]; bbv[j] = be[c0+j];
    }
    ushort4 hs = *(const ushort4*)&cur[(size_t)n*SEM + c0];
    acc[0]=b2f(hs.x); acc[1]=b2f(hs.y); acc[2]=b2f(hs.z); acc[3]=b2f(hs.w);
    int k  = indptr[n], k1 = indptr[n+1];

    auto accum4 = [&](float4 e0, float4 e1, float4 e2, float4 e3,
                      ushort4 ha, ushort4 hb, ushort4 hc, ushort4 hd){
        float fa[4] = {b2f(ha.x), b2f(ha.y), b2f(ha.z), b2f(ha.w)};
        float fb[4] = {b2f(hb.x), b2f(hb.y), b2f(hb.z), b2f(hb.w)};
        float fc[4] = {b2f(hc.x), b2f(hc.y), b2f(hc.z), b2f(hc.w)};
        float fd[4] = {b2f(hd.x), b2f(hd.y), b2f(hd.z), b2f(hd.w)};
        #pragma unroll
        for (int j=0;j<4;j++){
            float va = fa[j] + e0.y*w0[j] + e0.z*w1[j] + e0.w*w2[j] + bbv[j];
            float vb = fb[j] + e1.y*w0[j] + e1.z*w1[j] + e1.w*w2[j] + bbv[j];
            float vc = fc[j] + e2.y*w0[j] + e2.z*w1[j] + e2.w*w2[j] + bbv[j];
            float vd = fd[j] + e3.y*w0[j] + e3.z*w1[j] + e3.w*w2[j] + bbv[j];
            acc[j] += fmaxf(va, 0.f) + fmaxf(vb, 0.f) + fmaxf(vc, 0.f) + fmaxf(vd, 0.f);
        }
    };

    if (k + 4 <= k1){
        float4 e0 = epack[k], e1 = epack[k+1], e2 = epack[k+2], e3 = epack[k+3];
        ushort4 h0 = *(const ushort4*)&cur[(size_t)__float_as_int(e0.x)*SEM + c0];
        ushort4 h1 = *(const ushort4*)&cur[(size_t)__float_as_int(e1.x)*SEM + c0];
        ushort4 h2 = *(const ushort4*)&cur[(size_t)__float_as_int(e2.x)*SEM + c0];
        ushort4 h3 = *(const ushort4*)&cur[(size_t)__float_as_int(e3.x)*SEM + c0];
        while (k + 8 <= k1){
            float4 f0 = epack[k+4], f1 = epack[k+5], f2 = epack[k+6], f3 = epack[k+7];
            ushort4 g0 = *(const ushort4*)&cur[(size_t)__float_as_int(f0.x)*SEM + c0];
            ushort4 g1 = *(const ushort4*)&cur[(size_t)__float_as_int(f1.x)*SEM + c0];
            ushort4 g2 = *(const ushort4*)&cur[(size_t)__float_as_int(f2.x)*SEM + c0];
            ushort4 g3 = *(const ushort4*)&cur[(size_t)__float_as_int(f3.x)*SEM + c0];
            accum4(e0,e1,e2,e3, h0,h1,h2,h3);
            e0=f0; e1=f1; e2=f2; e3=f3;
            h0=g0; h1=g1; h2=g2; h3=g3;
            k += 4;
        }
        accum4(e0,e1,e2,e3, h0,h1,h2,h3);
        k += 4;
    }
    for (; k < k1; k++){
        float4 e0 = epack[k];
        int s0 = __float_as_int(e0.x);
        ushort4 ha = *(const ushort4*)&cur[(size_t)s0*SEM + c0];
        float fa[4] = {b2f(ha.x), b2f(ha.y), b2f(ha.z), b2f(ha.w)};
        #pragma unroll
        for (int j=0;j<4;j++){
            float va = fa[j] + e0.y*w0[j] + e0.z*w1[j] + e0.w*w2[j] + bbv[j];
            acc[j] += fmaxf(va, 0.f);
        }
    }
    ushort4 o;
    o.x = __bfloat16_as_ushort(tob(acc[0]));
    o.y = __bfloat16_as_ushort(tob(acc[1]));
    o.z = __bfloat16_as_ushort(tob(acc[2]));
    o.w = __bfloat16_as_ushort(tob(acc[3]));
    *(ushort4*)&apx[(size_t)n*SEM + c0] = o;
}

__global__ __launch_bounds__(256) void k_agg4(const bf16* __restrict__ cur, const float* __restrict__ We,
                      const float* __restrict__ be, const float4* __restrict__ epack,
                      const int* __restrict__ indptr, bf16* __restrict__ apx){
    int idx = blockIdx.x*256 + threadIdx.x;
    if (idx >= NN*CG) return;
    agg4_body(cur, We, be, epack, indptr, apx, idx);
}

// ---------------- dual agg: one gather pass feeds BOTH weight sets (layer-0 fusion) ----------------
__global__ __launch_bounds__(256) void k_agg4d(const bf16* __restrict__ cur,
                      const float* __restrict__ WeA, const float* __restrict__ beA,
                      const float* __restrict__ WeB, const float* __restrict__ beB,
                      const float4* __restrict__ epack, const int* __restrict__ indptr,
                      bf16* __restrict__ apxA, bf16* __restrict__ apxB){
    int idx = blockIdx.x*256 + threadIdx.x;
    if (idx >= NN*CG) return;
    int n = idx / CG, cg = idx - n*CG;
    int c0 = cg*4;
    float a0[4], a1[4], a2[4], ab[4], accA[4];
    float b0[4], b1[4], b2[4], bb[4], accB[4];
    #pragma unroll
    for (int j=0;j<4;j++){
        a0[j]=WeA[c0+j]; a1[j]=WeA[EMB+c0+j]; a2[j]=WeA[2*EMB+c0+j]; ab[j]=beA[c0+j];
        b0[j]=WeB[c0+j]; b1[j]=WeB[EMB+c0+j]; b2[j]=WeB[2*EMB+c0+j]; bb[j]=beB[c0+j];
    }
    ushort4 hs = *(const ushort4*)&cur[(size_t)n*SEM + c0];
    float fs[4] = {b2f(hs.x), b2f(hs.y), b2f(hs.z), b2f(hs.w)};
    #pragma unroll
    for (int j=0;j<4;j++){ accA[j]=fs[j]; accB[j]=fs[j]; }
    int k = indptr[n], k1 = indptr[n+1];
    for (; k+2 <= k1; k += 2){
        float4 e0 = epack[k], e1 = epack[k+1];
        int s0 = __float_as_int(e0.x), s1 = __float_as_int(e1.x);
        ushort4 ha = *(const ushort4*)&cur[(size_t)s0*SEM + c0];
        ushort4 hb = *(const ushort4*)&cur[(size_t)s1*SEM + c0];
        float fa[4] = {b2f(ha.x), b2f(ha.y), b2f(ha.z), b2f(ha.w)};
        float fb[4] = {b2f(hb.x), b2f(hb.y), b2f(hb.z), b2f(hb.w)};
        #pragma unroll
        for (int j=0;j<4;j++){
            accA[j] += fmaxf(fa[j] + e0.y*a0[j] + e0.z*a1[j] + e0.w*a2[j] + ab[j], 0.f)
                     + fmaxf(fb[j] + e1.y*a0[j] + e1.z*a1[j] + e1.w*a2[j] + ab[j], 0.f);
            accB[j] += fmaxf(fa[j] + e0.y*b0[j] + e0.z*b1[j] + e0.w*b2[j] + bb[j], 0.f)
                     + fmaxf(fb[j] + e1.y*b0[j] + e1.z*b1[j] + e1.w*b2[j] + bb[j], 0.f);
        }
    }
    if (k < k1){
        float4 e0 = epack[k];
        int s0 = __float_as_int(e0.x);
        ushort4 ha = *(const ushort4*)&cur[(size_t)s0*SEM + c0];
        float fa[4] = {b2f(ha.x), b2f(ha.y), b2f(ha.z), b2f(ha.w)};
        #pragma unroll
        for (int j=0;j<4;j++){
            accA[j] += fmaxf(fa[j] + e0.y*a0[j] + e0.z*a1[j] + e0.w*a2[j] + ab[j], 0.f);
            accB[j] += fmaxf(fa[j] + e0.y*b0[j] + e0.z*b1[j] + e0.w*b2[j] + bb[j], 0.f);
        }
    }
    ushort4 oA, oB;
    oA.x=__bfloat16_as_ushort(tob(accA[0])); oA.y=__bfloat16_as_ushort(tob(accA[1]));
    oA.z=__bfloat16_as_ushort(tob(accA[2])); oA.w=__bfloat16_as_ushort(tob(accA[3]));
    oB.x=__bfloat16_as_ushort(tob(accB[0])); oB.y=__bfloat16_as_ushort(tob(accB[1]));
    oB.z=__bfloat16_as_ushort(tob(accB[2])); oB.w=__bfloat16_as_ushort(tob(accB[3]));
    *(ushort4*)&apxA[(size_t)n*SEM + c0] = oA;
    *(ushort4*)&apxB[(size_t)n*SEM + c0] = oB;
}

// ---------------- dual-SOURCE agg (layer 1): one epack pass gathers from BOTH residual streams ----
// replaces the z-paired form: halves epack loads + address math; 2 gathers in flight per edge.
__global__ __launch_bounds__(256) void k_agg4dd(const bf16* __restrict__ curA, const bf16* __restrict__ curB,
                      const float* __restrict__ WeA, const float* __restrict__ beA,
                      const float* __restrict__ WeB, const float* __restrict__ beB,
                      const float4* __restrict__ epack, const int* __restrict__ indptr,
                      bf16* __restrict__ apxA, bf16* __restrict__ apxB){
    int idx = blockIdx.x*256 + threadIdx.x;
    if (idx >= NN*CG) return;
    int n = idx / CG, cg = idx - n*CG;
    int c0 = cg*4;
    float a0[4], a1[4], a2[4], ab[4], accA[4];
    float b0[4], b1[4], b2[4], bb[4], accB[4];
    #pragma unroll
    for (int j=0;j<4;j++){
        a0[j]=WeA[c0+j]; a1[j]=WeA[EMB+c0+j]; a2[j]=WeA[2*EMB+c0+j]; ab[j]=beA[c0+j];
        b0[j]=WeB[c0+j]; b1[j]=WeB[EMB+c0+j]; b2[j]=WeB[2*EMB+c0+j]; bb[j]=beB[c0+j];
    }
    ushort4 hsA = *(const ushort4*)&curA[(size_t)n*SEM + c0];
    ushort4 hsB = *(const ushort4*)&curB[(size_t)n*SEM + c0];
    accA[0]=b2f(hsA.x); accA[1]=b2f(hsA.y); accA[2]=b2f(hsA.z); accA[3]=b2f(hsA.w);
    accB[0]=b2f(hsB.x); accB[1]=b2f(hsB.y); accB[2]=b2f(hsB.z); accB[3]=b2f(hsB.w);
    int k = indptr[n], k1 = indptr[n+1];
    for (; k+2 <= k1; k += 2){
        float4 e0 = epack[k], e1 = epack[k+1];
        int s0 = __float_as_int(e0.x), s1 = __float_as_int(e1.x);
        ushort4 ha = *(const ushort4*)&curA[(size_t)s0*SEM + c0];
        ushort4 hb = *(const ushort4*)&curA[(size_t)s1*SEM + c0];
        ushort4 hc = *(const ushort4*)&curB[(size_t)s0*SEM + c0];
        ushort4 hd = *(const ushort4*)&curB[(size_t)s1*SEM + c0];
        float fa[4] = {b2f(ha.x), b2f(ha.y), b2f(ha.z), b2f(ha.w)};
        float fb[4] = {b2f(hb.x), b2f(hb.y), b2f(hb.z), b2f(hb.w)};
        float fc[4] = {b2f(hc.x), b2f(hc.y), b2f(hc.z), b2f(hc.w)};
        float fd[4] = {b2f(hd.x), b2f(hd.y), b2f(hd.z), b2f(hd.w)};
        #pragma unroll
        for (int j=0;j<4;j++){
            accA[j] += fmaxf(fa[j] + e0.y*a0[j] + e0.z*a1[j] + e0.w*a2[j] + ab[j], 0.f)
                     + fmaxf(fb[j] + e1.y*a0[j] + e1.z*a1[j] + e1.w*a2[j] + ab[j], 0.f);
            accB[j] += fmaxf(fc[j] + e0.y*b0[j] + e0.z*b1[j] + e0.w*b2[j] + bb[j], 0.f)
                     + fmaxf(fd[j] + e1.y*b0[j] + e1.z*b1[j] + e1.w*b2[j] + bb[j], 0.f);
        }
    }
    if (k < k1){
        float4 e0 = epack[k];
        int s0 = __float_as_int(e0.x);
        ushort4 ha = *(const ushort4*)&curA[(size_t)s0*SEM + c0];
        ushort4 hc = *(const ushort4*)&curB[(size_t)s0*SEM + c0];
        float fa[4] = {b2f(ha.x), b2f(ha.y), b2f(ha.z), b2f(ha.w)};
        float fc[4] = {b2f(hc.x), b2f(hc.y), b2f(hc.z), b2f(hc.w)};
        #pragma unroll
        for (int j=0;j<4;j++){
            accA[j] += fmaxf(fa[j] + e0.y*a0[j] + e0.z*a1[j] + e0.w*a2[j] + ab[j], 0.f);
            accB[j] += fmaxf(fc[j] + e0.y*b0[j] + e0.z*b1[j] + e0.w*b2[j] + bb[j], 0.f);
        }
    }
    ushort4 oA, oB;
    oA.x=__bfloat16_as_ushort(tob(accA[0])); oA.y=__bfloat16_as_ushort(tob(accA[1]));
    oA.z=__bfloat16_as_ushort(tob(accA[2])); oA.w=__bfloat16_as_ushort(tob(accA[3]));
    oB.x=__bfloat16_as_ushort(tob(accB[0])); oB.y=__bfloat16_as_ushort(tob(accB[1]));
    oB.z=__bfloat16_as_ushort(tob(accB[2])); oB.w=__bfloat16_as_ushort(tob(accB[3]));
    *(ushort4*)&apxA[(size_t)n*SEM + c0] = oA;
    *(ushort4*)&apxB[(size_t)n*SEM + c0] = oB;
}

// ---------------- MFMA bf16 GEMM body (BN=128): reg-staged dbuf K-loop ----------------
// Reg-staging (not global_load_lds): register loads stay in flight across the barrier (round-1
// lesson). Used for N=600 GEMMs, gatepair, simhead.
__device__ __forceinline__ void gemm_body(const bf16* __restrict__ A, const bf16* __restrict__ Bt,
        const float* __restrict__ bias, const bf16* __restrict__ R, bf16* __restrict__ C,
        int M, int N, int Kp, int ldc, int relu_out, short* lds, int m0, int n0){
    short* Ct = lds;
    const int CS = 136;
    int tid = threadIdx.x;
    int wave = tid >> 6, lane = tid & 63;
    int wm = wave >> 1, wn = wave & 1;

    int srow = tid >> 1;
    int sq   = (tid & 1) * 2;
    int grA = min(m0 + srow, M-1);
    int grB = min(n0 + srow, N-1);
    const bf16* pA = A  + (size_t)grA*Kp + sq*8;
    const bf16* pB = Bt + (size_t)grB*Kp + sq*8;
    int aoff0 = ((srow>>4)*64 +  sq   *16 + (srow&15))*8;
    int aoff1 = ((srow>>4)*64 + (sq+1)*16 + (srow&15))*8;

    f32x4 acc[4][4];
    #pragma unroll
    for (int i=0;i<4;i++){
        #pragma unroll
        for (int j=0;j<4;j++) acc[i][j] = (f32x4){0.f,0.f,0.f,0.f};
    }

    int KC = Kp >> 5;
    uint4 ra0 = *(const uint4*)(pA);
    uint4 ra1 = *(const uint4*)(pA + 8);
    uint4 rb0 = *(const uint4*)(pB);
    uint4 rb1 = *(const uint4*)(pB + 8);
    *(uint4*)(lds + aoff0)        = ra0;
    *(uint4*)(lds + aoff1)        = ra1;
    *(uint4*)(lds + 4096 + aoff0) = rb0;
    *(uint4*)(lds + 4096 + aoff1) = rb1;
    __syncthreads();
    if (KC > 1){
        ra0 = *(const uint4*)(pA + 32); ra1 = *(const uint4*)(pA + 40);
        rb0 = *(const uint4*)(pB + 32); rb1 = *(const uint4*)(pB + 40);
    }

    for (int kc=0; kc<KC; ++kc){
        short* cbuf = lds + (kc & 1)*8192;
        short* nbuf = lds + ((kc+1) & 1)*8192;
        if (kc+1 < KC){
            *(uint4*)(nbuf + aoff0)        = ra0;
            *(uint4*)(nbuf + aoff1)        = ra1;
            *(uint4*)(nbuf + 4096 + aoff0) = rb0;
            *(uint4*)(nbuf + 4096 + aoff1) = rb1;
            if (kc+2 < KC){
                const bf16* qA = pA + (kc+2)*32;
                const bf16* qB = pB + (kc+2)*32;
                ra0 = *(const uint4*)(qA); ra1 = *(const uint4*)(qA+8);
                rb0 = *(const uint4*)(qB); rb1 = *(const uint4*)(qB+8);
            }
        }
        bf16x8 af[4], bfr[4];
        #pragma unroll
        for (int i=0;i<4;i++) af[i]  = *(const bf16x8*)(cbuf + ((wm*4+i)*64 + lane)*8);
        #pragma unroll
        for (int j=0;j<4;j++) bfr[j] = *(const bf16x8*)(cbuf + 4096 + ((wn*4+j)*64 + lane)*8);
        #pragma unroll
        for (int i=0;i<4;i++){
            #pragma unroll
            for (int j=0;j<4;j++)
                acc[i][j] = __builtin_amdgcn_mfma_f32_16x16x32_bf16(af[i], bfr[j], acc[i][j], 0, 0, 0);
        }
        __syncthreads();
    }

    int lq = lane >> 4, lr = lane & 15;
    #pragma unroll
    for (int i=0;i<4;i++){
        int rl = (wm*4+i)*16 + lq*4;
        #pragma unroll
        for (int j=0;j<4;j++){
            int cl = (wn*4+j)*16 + lr;
            float bv = bias[min(n0+cl, N-1)];
            #pragma unroll
            for (int r=0;r<4;r++){
                float v = acc[i][j][r] + bv;
                if (relu_out) v = fmaxf(v, 0.f);
                Ct[(rl+r)*CS + cl] = (short)__bfloat16_as_ushort(tob(v));
            }
        }
    }
    __syncthreads();
    #pragma unroll
    for (int p=0;p<8;p++){
        int rl = p*16 + (tid>>4);
        int cl = (tid&15)*8;
        int row = m0 + rl, col = n0 + cl;
        if (row < M && col < N){
            union { short s8[8]; uint4 v; } u;
            u.v = *(uint4*)&Ct[rl*CS + cl];
            if (R){
                const bf16* rp = &R[(size_t)row*ldc + col];
                #pragma unroll
                for (int e=0;e<8;e++){
                    float v = b2f((unsigned short)u.s8[e]) + tof(rp[e]);
                    u.s8[e] = (short)__bfloat16_as_ushort(tob(v));
                }
            }
            *(uint4*)&C[(size_t)row*ldc + col] = u.v;
        }
    }
}

__global__ __launch_bounds__(256) void k_gemm2(const bf16* __restrict__ A, const bf16* __restrict__ Bt,
        const float* __restrict__ bias, const bf16* __restrict__ R, bf16* __restrict__ C,
        int M, int N, int Kp, int ldc, int relu_out){
    __shared__ __align__(16) char ldsbuf[34816];
    int nwg = gridDim.x*gridDim.y;
    int w = xcd_swz(blockIdx.y*gridDim.x + blockIdx.x, nwg);
    gemm_body(A, Bt, bias, R, C, M, N, Kp, ldc, relu_out, (short*)ldsbuf,
              (w/gridDim.x)*128, (w%gridDim.x)*128);
}

__global__ __launch_bounds__(256) void k_gemm2z(
        const bf16* __restrict__ A0, const bf16* __restrict__ A1,
        const bf16* __restrict__ Bt0, const bf16* __restrict__ Bt1,
        const float* __restrict__ bias0, const float* __restrict__ bias1,
        const bf16* __restrict__ R0, const bf16* __restrict__ R1,
        bf16* __restrict__ C0, bf16* __restrict__ C1,
        int M, int N, int Kp, int ldc, int relu0, int relu1){
    __shared__ __align__(16) char ldsbuf[34816];
    int nwg = gridDim.x*gridDim.y;
    int w = xcd_swz(blockIdx.y*gridDim.x + blockIdx.x, nwg);
    int m0 = (w/gridDim.x)*128, n0 = (w%gridDim.x)*128;
    if (blockIdx.z == 0) gemm_body(A0, Bt0, bias0, R0, C0, M, N, Kp, ldc, relu0, (short*)ldsbuf, m0, n0);
    else                 gemm_body(A1, Bt1, bias1, R1, C1, M, N, Kp, ldc, relu1, (short*)ldsbuf, m0, n0);
}

// ---------------- BN=160 GEMM body: for N=300 outputs ----------------
// vs BN=128 (3 col-tiles, 384 cols): 2 col-tiles -> A re-fetched 2x not 3x AND cols 320 not 384.
// LDS per buffer: A 4096 + B 5120 shorts (stride 9216 shorts); Ct 128x168 = 43008 B total.
__device__ __forceinline__ void gemm160_body(const bf16* __restrict__ A, const bf16* __restrict__ Bt,
        const float* __restrict__ bias, const bf16* __restrict__ R, bf16* __restrict__ C,
        int M, int N, int Kp, int ldc, int relu_out, short* lds, int m0, int n0){
    short* Ct = lds;
    const int CS = 168;
    const int BUF = 9216;   // shorts per dbuf half
    int tid = threadIdx.x;
    int wave = tid >> 6, lane = tid & 63;
    int wm = wave >> 1, wn = wave & 1;

    // A staging: 512 16B chunks, 2/thread
    int srow = tid >> 1;
    int sq   = (tid & 1) * 2;
    int grA = min(m0 + srow, M-1);
    const bf16* pA = A + (size_t)grA*Kp + sq*8;
    int aoff0 = ((srow>>4)*64 +  sq   *16 + (srow&15))*8;
    int aoff1 = ((srow>>4)*64 + (sq+1)*16 + (srow&15))*8;

    // B staging: 640 16B chunks: tid, tid+256, and tid+512 for tid<128 (wave-uniform split)
    int cB0 = tid, cB1 = tid + 256, cB2 = tid + 512;
    int br0 = cB0>>2, bq0 = cB0&3;
    int br1 = cB1>>2, bq1 = cB1&3;
    int br2 = cB2>>2, bq2 = cB2&3;
    const bf16* pB0 = Bt + (size_t)min(n0+br0, N-1)*Kp + bq0*8;
    const bf16* pB1 = Bt + (size_t)min(n0+br1, N-1)*Kp + bq1*8;
    const bf16* pB2 = Bt + (size_t)min(n0+br2, N-1)*Kp + bq2*8;
    int boff0 = 4096 + ((br0>>4)*64 + bq0*16 + (br0&15))*8;
    int boff1 = 4096 + ((br1>>4)*64 + bq1*16 + (br1&15))*8;
    int boff2 = 4096 + ((br2>>4)*64 + bq2*16 + (br2&15))*8;
    bool b3 = (tid < 128);

    f32x4 acc[4][5];
    #pragma unroll
    for (int i=0;i<4;i++){
        #pragma unroll
        for (int j=0;j<5;j++) acc[i][j] = (f32x4){0.f,0.f,0.f,0.f};
    }

    int KC = Kp >> 5;
    uint4 ra0 = *(const uint4*)(pA);
    uint4 ra1 = *(const uint4*)(pA + 8);
    uint4 rb0 = *(const uint4*)(pB0);
    uint4 rb1 = *(const uint4*)(pB1);
    uint4 rb2 = {0,0,0,0};
    if (b3) rb2 = *(const uint4*)(pB2);
    *(uint4*)(lds + aoff0) = ra0;
    *(uint4*)(lds + aoff1) = ra1;
    *(uint4*)(lds + boff0) = rb0;
    *(uint4*)(lds + boff1) = rb1;
    if (b3) *(uint4*)(lds + boff2) = rb2;
    __syncthreads();
    if (KC > 1){
        ra0 = *(const uint4*)(pA + 32);  ra1 = *(const uint4*)(pA + 40);
        rb0 = *(const uint4*)(pB0 + 32); rb1 = *(const uint4*)(pB1 + 32);
        if (b3) rb2 = *(const uint4*)(pB2 + 32);
    }

    for (int kc=0; kc<KC; ++kc){
        short* cbuf = lds + (kc & 1)*BUF;
        short* nbuf = lds + ((kc+1) & 1)*BUF;
        if (kc+1 < KC){
            *(uint4*)(nbuf + aoff0) = ra0;
            *(uint4*)(nbuf + aoff1) = ra1;
            *(uint4*)(nbuf + boff0) = rb0;
            *(uint4*)(nbuf + boff1) = rb1;
            if (b3) *(uint4*)(nbuf + boff2) = rb2;
            if (kc+2 < KC){
                const bf16* qA = pA + (kc+2)*32;
                ra0 = *(const uint4*)(qA); ra1 = *(const uint4*)(qA+8);
                rb0 = *(const uint4*)(pB0 + (kc+2)*32);
                rb1 = *(const uint4*)(pB1 + (kc+2)*32);
                if (b3) rb2 = *(const uint4*)(pB2 + (kc+2)*32);
            }
        }
        bf16x8 af[4], bfr[5];
        #pragma unroll
        for (int i=0;i<4;i++) af[i]  = *(const bf16x8*)(cbuf + ((wm*4+i)*64 + lane)*8);
        #pragma unroll
        for (int j=0;j<5;j++) bfr[j] = *(const bf16x8*)(cbuf + 4096 + ((wn*5+j)*64 + lane)*8);
        #pragma unroll
        for (int i=0;i<4;i++){
            #pragma unroll
            for (int j=0;j<5;j++)
                acc[i][j] = __builtin_amdgcn_mfma_f32_16x16x32_bf16(af[i], bfr[j], acc[i][j], 0, 0, 0);
        }
        __syncthreads();
    }

    int lq = lane >> 4, lr = lane & 15;
    #pragma unroll
    for (int i=0;i<4;i++){
        int rl = (wm*4+i)*16 + lq*4;
        #pragma unroll
        for (int j=0;j<5;j++){
            int cl = (wn*5+j)*16 + lr;
            float bv = bias[min(n0+cl, N-1)];
            #pragma unroll
            for (int r=0;r<4;r++){
                float v = acc[i][j][r] + bv;
                if (relu_out) v = fmaxf(v, 0.f);
                Ct[(rl+r)*CS + cl] = (short)__bfloat16_as_ushort(tob(v));
            }
        }
    }
    __syncthreads();
    // writeout: 128 rows x 20 col-chunks(8) = 2560 chunks, 10/thread
    #pragma unroll
    for (int p=0;p<10;p++){
        int c = p*256 + tid;
        int row = c / 20, colc = c - (c/20)*20;
        int grow = m0 + row, gcol = n0 + colc*8;
        if (grow < M && gcol < N){
            union { short s8[8]; uint4 v; } u;
            u.v = *(uint4*)&Ct[row*CS + colc*8];
            if (R){
                const bf16* rp = &R[(size_t)grow*ldc + gcol];
                #pragma unroll
                for (int e=0;e<8;e++){
                    float v = b2f((unsigned short)u.s8[e]) + tof(rp[e]);
                    u.s8[e] = (short)__bfloat16_as_ushort(tob(v));
                }
            }
            *(uint4*)&C[(size_t)grow*ldc + gcol] = u.v;
        }
    }
}

__global__ __launch_bounds__(256) void k_gemm160(const bf16* __restrict__ A, const bf16* __restrict__ Bt,
        const float* __restrict__ bias, const bf16* __restrict__ R, bf16* __restrict__ C,
        int M, int N, int Kp, int ldc, int relu_out, int mBase){
    __shared__ __align__(16) char ldsbuf[43008];
    int nwg = gridDim.x*gridDim.y;
    int w = xcd_swz(blockIdx.y*gridDim.x + blockIdx.x, nwg);
    gemm160_body(A, Bt, bias, R, C, M, N, Kp, ldc, relu_out, (short*)ldsbuf,
                 mBase + (w/gridDim.x)*128, (w%gridDim.x)*160);
}

__global__ __launch_bounds__(256) void k_gemm160z(
        const bf16* __restrict__ A0, const bf16* __restrict__ A1,
        const bf16* __restrict__ Bt0, const bf16* __restrict__ Bt1,
        const float* __restrict__ bias0, const float* __restrict__ bias1,
        const bf16* __restrict__ R0, const bf16* __restrict__ R1,
        bf16* __restrict__ C0, bf16* __restrict__ C1,
        int M, int N, int Kp, int ldc, int relu0, int relu1){
    __shared__ __align__(16) char ldsbuf[43008];
    int nwg = gridDim.x*gridDim.y;
    int w = xcd_swz(blockIdx.y*gridDim.x + blockIdx.x, nwg);
    int m0 = (w/gridDim.x)*128, n0 = (w%gridDim.x)*160;
    if (blockIdx.z == 0) gemm160_body(A0, Bt0, bias0, R0, C0, M, N, Kp, ldc, relu0, (short*)ldsbuf, m0, n0);
    else                 gemm160_body(A1, Bt1, bias1, R1, C1, M, N, Kp, ldc, relu1, (short*)ldsbuf, m0, n0);
}

// row-split hetero pair (l3/l4): [0,585) g1 rows [MS,NN) ∥ [585,821) g160 rows [0,MS)
__global__ __launch_bounds__(256) void k_g1g160(
        const bf16* __restrict__ A0, const bf16* __restrict__ Bt0, const float* __restrict__ b0,
        bf16* __restrict__ C0,
        const bf16* __restrict__ A1, const bf16* __restrict__ Bt1, const float* __restrict__ b1,
        const bf16* __restrict__ R1, bf16* __restrict__ C1, int relu1){
    __shared__ __align__(16) char ldsbuf[43008];
    int bid = blockIdx.x;
    if (bid < 585){
        int w = xcd_swz(bid, 585);
        gemm_body(A0, Bt0, b0, nullptr, C0, NN, HID, SEM, SHID, 1, (short*)ldsbuf,
                  MS + (w/5)*128, (w%5)*128);
    } else {
        int w = xcd_swz(bid - 585, 236);
        gemm160_body(A1, Bt1, b1, R1, C1, NN, EMB, SHID, SEM, relu1, (short*)ldsbuf,
                     (w>>1)*128, (w&1)*160);
    }
}

// enc-l2 g2 (BN160) + gate finisher in one dispatch: [0,470) gemm blocks, [470,588) gate blocks
__global__ __launch_bounds__(256) void k_g160gate(
        const bf16* __restrict__ A, const bf16* __restrict__ Bt, const float* __restrict__ bias,
        const bf16* __restrict__ R, bf16* __restrict__ C,
        const float* __restrict__ glogit, const float* __restrict__ bg2,
        const float* __restrict__ gumbel, float* __restrict__ gate){
    __shared__ __align__(16) char ldsbuf[43008];
    int bid = blockIdx.x;
    if (bid < 470){
        int w = xcd_swz(bid, 470);
        gemm160_body(A, Bt, bias, R, C, NN, EMB, SHID, SEM, 1, (short*)ldsbuf,
                     (w>>1)*128, (w&1)*160);
    } else {
        int i = (bid-470)*256 + threadIdx.x;
        if (i >= NN) return;
        float l0 = glogit[2*i]   + bg2[0] + gumbel[2*i];
        float l1 = glogit[2*i+1] + bg2[1] + gumbel[2*i+1];
        float m = fmaxf(l0, l1);
        float e0 = expf(l0-m), e1 = expf(l1-m);
        gate[i] = e1/(e0+e1);
    }
}

// ---------------- gate GEMM: logits from acc registers, no C write ----------------
// logit[row][t] = sum_col relu(acc+bias) * Wg2[col*2+t]; 16-lane shfl reduce + atomicAdd.
__device__ __forceinline__ void gate_gemm_body(const bf16* __restrict__ A, const bf16* __restrict__ Bt,
        const float* __restrict__ bias, const float* __restrict__ Wg2, float* __restrict__ glogit,
        int M, int N, int Kp, short* lds, int m0, int n0){
    int tid = threadIdx.x;
    int wave = tid >> 6, lane = tid & 63;
    int wm = wave >> 1, wn = wave & 1;

    int srow = tid >> 1;
    int sq   = (tid & 1) * 2;
    int grA = min(m0 + srow, M-1);
    int grB = min(n0 + srow, N-1);
    const bf16* pA = A  + (size_t)grA*Kp + sq*8;
    const bf16* pB = Bt + (size_t)grB*Kp + sq*8;
    int aoff0 = ((srow>>4)*64 +  sq   *16 + (srow&15))*8;
    int aoff1 = ((srow>>4)*64 + (sq+1)*16 + (srow&15))*8;

    f32x4 acc[4][4];
    #pragma unroll
    for (int i=0;i<4;i++){
        #pragma unroll
        for (int j=0;j<4;j++) acc[i][j] = (f32x4){0.f,0.f,0.f,0.f};
    }

    int KC = Kp >> 5;
    uint4 ra0 = *(const uint4*)(pA);
    uint4 ra1 = *(const uint4*)(pA + 8);
    uint4 rb0 = *(const uint4*)(pB);
    uint4 rb1 = *(const uint4*)(pB + 8);
    *(uint4*)(lds + aoff0)        = ra0;
    *(uint4*)(lds + aoff1)        = ra1;
    *(uint4*)(lds + 4096 + aoff0) = rb0;
    *(uint4*)(lds + 4096 + aoff1) = rb1;
    __syncthreads();
    if (KC > 1){
        ra0 = *(const uint4*)(pA + 32); ra1 = *(const uint4*)(pA + 40);
        rb0 = *(const uint4*)(pB + 32); rb1 = *(const uint4*)(pB + 40);
    }

    for (int kc=0; kc<KC; ++kc){
        short* cbuf = lds + (kc & 1)*8192;
        short* nbuf = lds + ((kc+1) & 1)*8192;
        if (kc+1 < KC){
            *(uint4*)(nbuf + aoff0)        = ra0;
            *(uint4*)(nbuf + aoff1)        = ra1;
            *(uint4*)(nbuf + 4096 + aoff0) = rb0;
            *(uint4*)(nbuf + 4096 + aoff1) = rb1;
            if (kc+2 < KC){
                const bf16* qA = pA + (kc+2)*32;
                const bf16* qB = pB + (kc+2)*32;
                ra0 = *(const uint4*)(qA); ra1 = *(const uint4*)(qA+8);
                rb0 = *(const uint4*)(qB); rb1 = *(const uint4*)(qB+8);
            }
        }
        bf16x8 af[4], bfr[4];
        #pragma unroll
        for (int i=0;i<4;i++) af[i]  = *(const bf16x8*)(cbuf + ((wm*4+i)*64 + lane)*8);
        #pragma unroll
        for (int j=0;j<4;j++) bfr[j] = *(const bf16x8*)(cbuf + 4096 + ((wn*4+j)*64 + lane)*8);
        #pragma unroll
        for (int i=0;i<4;i++){
            #pragma unroll
            for (int j=0;j<4;j++)
                acc[i][j] = __builtin_amdgcn_mfma_f32_16x16x32_bf16(af[i], bfr[j], acc[i][j], 0, 0, 0);
        }
        __syncthreads();
    }

    int lq = lane >> 4, lr = lane & 15;
    #pragma unroll
    for (int i=0;i<4;i++){
        #pragma unroll
        for (int r=0;r<4;r++){
            int row = m0 + (wm*4+i)*16 + lq*4 + r;
            float p0 = 0.f, p1 = 0.f;
            #pragma unroll
            for (int j=0;j<4;j++){
                int cl = (wn*4+j)*16 + lr;
                int col = n0 + cl;
                float v = fmaxf(acc[i][j][r] + bias[min(col, N-1)], 0.f);
                if (col < N){ p0 += v * Wg2[col*2]; p1 += v * Wg2[col*2+1]; }
            }
            #pragma unroll
            for (int m=1; m<16; m<<=1){ p0 += __shfl_xor(p0, m); p1 += __shfl_xor(p1, m); }
            if (lr == 0 && row < M){
                atomicAdd(&glogit[row*2],   p0);
                atomicAdd(&glogit[row*2+1], p1);
            }
        }
    }
}

// hetero pair: [0,1175) gate-gemm (cur_r @ Wg1 -> logits), [1175,2350) enc-l2 g1 (normal)
__global__ __launch_bounds__(256) void k_gatepair(
        const bf16* __restrict__ Ag, const bf16* __restrict__ Btg, const float* __restrict__ bg,
        const float* __restrict__ Wg2, float* __restrict__ glogit,
        const bf16* __restrict__ A1, const bf16* __restrict__ Bt1, const float* __restrict__ b1,
        bf16* __restrict__ C1){
    __shared__ __align__(16) char ldsbuf[34816];
    int bid = blockIdx.x;
    if (bid < 1175){
        int w = xcd_swz(bid, 1175);
        gate_gemm_body(Ag, Btg, bg, Wg2, glogit, NN, HID, SEM, (short*)ldsbuf,
                       (w/5)*128, (w%5)*128);
    } else {
        int w = xcd_swz(bid - 1175, 1175);
        gemm_body(A1, Bt1, b1, nullptr, C1, NN, HID, SEM, SHID, 1, (short*)ldsbuf,
                  (w/5)*128, (w%5)*128);
    }
}

// ---------------- sim machinery (device) ----------------
__device__ __forceinline__ void stage_tile(const short* __restrict__ P, int RB, int K, int r0, int k0,
                                           short (*lds)[64][8], int tid){
    #pragma unroll
    for (int s=0;s<2;s++){
        int seg = tid*2+s;
        int row = seg>>2, q = seg&3;
        int gr = r0 + row;
        int gk = k0 + q*8;
        union { short s8[8]; uint4 v; } u;
        if (gr < RB && gk + 8 <= K){
            const uint2* p = (const uint2*)(P + (size_t)gr*K + gk);
            uint2 lo = p[0], hi = p[1];
            u.v.x = lo.x; u.v.y = lo.y; u.v.z = hi.x; u.v.w = hi.y;
        } else {
            #pragma unroll
            for (int j=0;j<8;j++){
                int kk = gk + j;
                u.s8[j] = (gr < RB && kk < K) ? P[(size_t)gr*K + kk] : (short)0;
            }
        }
        *(uint4*)&lds[row>>4][q*16 + (row&15)][0] = u.v;
    }
}

// sim_cp rowsums: S[i] += sum_j exp((hr_i.henv_j)*5/(na_i*nc_j+1e-8)); matrix never materialized
__device__ __forceinline__ void sim_body(const bf16* __restrict__ A, const bf16* __restrict__ Bt,
                      const float* __restrict__ na, const float* __restrict__ nc, float* __restrict__ S,
                      char* ldsraw){
    short (*Asl)[64][8] = (short(*)[64][8])ldsraw;
    short (*Bsl)[64][8] = (short(*)[64][8])(ldsraw + 8192);
    int tid = threadIdx.x;
    int wave = tid >> 6, lane = tid & 63;
    int wm = wave >> 1, wn = wave & 1;
    int m0 = blockIdx.y*128, n0 = blockIdx.x*128;
    f32x4 acc[4][4];
    #pragma unroll
    for (int i=0;i<4;i++){
        #pragma unroll
        for (int j=0;j<4;j++) acc[i][j] = (f32x4){0.f,0.f,0.f,0.f};
    }
    for (int k0=0; k0<SEM; k0+=32){
        stage_tile((const short*)A,  NG, SEM, m0, k0, Asl, tid);
        stage_tile((const short*)Bt, NG, SEM, n0, k0, Bsl, tid);
        __syncthreads();
        bf16x8 af[4], bfr[4];
        #pragma unroll
        for (int i=0;i<4;i++) af[i]  = *(const bf16x8*)&Asl[wm*4+i][lane][0];
        #pragma unroll
        for (int j=0;j<4;j++) bfr[j] = *(const bf16x8*)&Bsl[wn*4+j][lane][0];
        #pragma unroll
        for (int i=0;i<4;i++){
            #pragma unroll
            for (int j=0;j<4;j++)
                acc[i][j] = __builtin_amdgcn_mfma_f32_16x16x32_bf16(af[i], bfr[j], acc[i][j], 0, 0, 0);
        }
        __syncthreads();
    }
    int lq = lane >> 4, lr = lane & 15;
    #pragma unroll
    for (int i=0;i<4;i++){
        #pragma unroll
        for (int r=0;r<4;r++){
            int row = m0 + (wm*4+i)*16 + lq*4 + r;
            float nar = na[min(row, NG-1)];
            float rsum = 0.f;
            #pragma unroll
            for (int j=0;j<4;j++){
                int col = n0 + (wn*4+j)*16 + lr;
                float ncj = nc[min(col, NG-1)];
                float e = expf(acc[i][j][r] * 5.0f / (nar*ncj + 1e-8f));
                if (row < NG && col < NG) rsum += e;
            }
            #pragma unroll
            for (int m=1; m<16; m<<=1) rsum += __shfl_xor(rsum, m);
            if (lr == 0 && row < NG) atomicAdd(&S[row], rsum);
        }
    }
}

// fat kernel: z=0 -> sim rowsums (grid 12x12), z=1 -> head GEMM (grid 5x24)
__global__ __launch_bounds__(256) void k_simhead(const bf16* __restrict__ hrb, const bf16* __restrict__ henvb,
        const float* __restrict__ na, const float* __restrict__ nc, float* __restrict__ Ssum,
        const bf16* __restrict__ Pbuf, const bf16* __restrict__ wtp1, const float* __restrict__ bp1,
        bf16* __restrict__ hidP){
    __shared__ __align__(16) char ldsbuf[34816];
    if (blockIdx.z == 0){
        if (blockIdx.x >= 12 || blockIdx.y >= 12) return;
        sim_body(hrb, henvb, na, nc, Ssum, ldsbuf);
    } else {
        if (blockIdx.x >= 5) return;
        gemm_body(Pbuf, wtp1, bp1, nullptr, hidP, 2*NG, HID, SEM, SHID, 1, (short*)ldsbuf,
                  blockIdx.y*128, blockIdx.x*128);
    }
}

// ---------------- fused pooling + mean + norms + P top half (one block per graph) ----------------
// sums stay in registers: kills the sumh/sumgh round-trip and the k_meannorm dispatch
__global__ __launch_bounds__(320) void k_poolmean(const bf16* __restrict__ h, const float* __restrict__ gate,
                      const int* __restrict__ gstart, float* __restrict__ hr, float* __restrict__ henv,
                      bf16* __restrict__ hrb, bf16* __restrict__ henvb, bf16* __restrict__ P,
                      float* __restrict__ na, float* __restrict__ nc, float* __restrict__ pos,
                      float* __restrict__ rnum, float* __restrict__ cntf, float* __restrict__ Ssum){
    int g = blockIdx.x, c = threadIdx.x;
    int n0 = gstart[g], n1 = gstart[g+1];
    float sh=0.f, sg=0.f, sgate=0.f;
    if (c < EMB){
        for (int n=n0;n<n1;n++){
            float v = tof(h[(size_t)n*SEM+c]);
            float gt = gate[n];
            sh += v; sg += gt*v;
            if (c==0) sgate += gt;
        }
    }
    float cnt = (float)(n1-n0);
    float inv = 1.f / fmaxf(cnt, 1.f);
    float r=0.f, e=0.f, o=0.f;
    int idx = g*SEM + c;
    if (c < EMB){
        int off = g*EMB + c;
        r = sg*inv; e = (sh-sg)*inv; o = sh*inv;
        hr[off] = r; henv[off] = e;
        hrb[idx] = tob(r); henvb[idx] = tob(e); P[idx] = tob(r);
        if (c==0){ rnum[g] = sgate; cntf[g] = cnt; }
    } else {
        hrb[idx] = tob(0.f); henvb[idx] = tob(0.f); P[idx] = tob(0.f);   // zero pads (B-operands!)
        if (c == 319) Ssum[g] = 0.f;
    }
    float srr=r*r, soo=o*o, see=e*e, sro=r*o;
    #pragma unroll
    for (int off=32; off>0; off>>=1){
        srr += __shfl_down(srr,off); soo += __shfl_down(soo,off);
        see += __shfl_down(see,off); sro += __shfl_down(sro,off);
    }
    __shared__ float ws[4][5];
    int wv = c >> 6, ln = c & 63;
    if (ln == 0){ ws[0][wv]=srr; ws[1][wv]=soo; ws[2][wv]=see; ws[3][wv]=sro; }
    __syncthreads();
    if (c == 0){
        float a=0.f,b=0.f,c2=0.f,d=0.f;
        #pragma unroll
        for (int i=0;i<5;i++){ a+=ws[0][i]; b+=ws[1][i]; c2+=ws[2][i]; d+=ws[3][i]; }
        float sa = sqrtf(a), sb = sqrtf(b), sc = sqrtf(c2);
        na[g] = sa; nc[g] = sc;
        pos[g] = expf(d/(sa*sb + 1e-8f) * 5.0f);
    }
}

// P bottom half: needs OTHER graphs' henv (perm) -> separate dispatch after k_poolmean
__global__ __launch_bounds__(256) void k_pbuild2(const float* __restrict__ hr, const float* __restrict__ henv,
                      const int* __restrict__ perm, bf16* __restrict__ P){
    int idx = blockIdx.x*256 + threadIdx.x;
    if (idx >= NG*SEM) return;
    int g = idx / SEM, c = idx - g*SEM;
    P[(size_t)(NG+g)*SEM + c] = (c < EMB)
        ? tob(hr[g*EMB+c] + henv[(size_t)perm[g]*EMB + c])
        : tob(0.f);
}

// pred (blocks 0..749) + loss (block 750) fused: all loss inputs ready before this dispatch
__global__ __launch_bounds__(256) void k_predloss(const bf16* __restrict__ hidP, const float* __restrict__ Wp2,
                      const float* __restrict__ bp2, const float* __restrict__ cntf,
                      const float* __restrict__ rnum, const float* __restrict__ pos,
                      const float* __restrict__ S, float* __restrict__ out){
    if (blockIdx.x == 750){
        __shared__ float ra[256], rb[256];
        int t = threadIdx.x;
        float a=0.f, b=0.f;
        for (int g=t; g<NG; g+=256){
            float r = rnum[g] + 1e-8f;
            float e = (cntf[g] - rnum[g]) + 1e-8f;
            a += fabsf(r/(r+e) - 0.4f);
            float p = pos[g];
            b += -logf(p/(S[g]+p));
        }
        ra[t]=a; rb[t]=b; __syncthreads();
        for (int off=128; off>0; off>>=1){ if (t<off){ ra[t]+=ra[t+off]; rb[t]+=rb[t+off]; } __syncthreads(); }
        if (t==0){
            out[2*NG*NTASK]   = ra[0]/NG;
            out[2*NG*NTASK+1] = rb[0]/NG;
        }
        return;
    }
    int r = blockIdx.x*4 + (threadIdx.x >> 6);
    int lane = threadIdx.x & 63;
    if (r >= 2*NG) return;
    float acc[NTASK];
    #pragma unroll
    for (int t=0;t<NTASK;t++) acc[t] = 0.f;
    for (int i=lane;i<HID;i+=64){
        float h = tof(hidP[(size_t)r*SHID+i]);
        const float4* wp = (const float4*)&Wp2[i*NTASK];
        float4 wa = wp[0], wb = wp[1], wc = wp[2];
        acc[0]+=h*wa.x; acc[1]+=h*wa.y; acc[2]+=h*wa.z; acc[3]+=h*wa.w;
        acc[4]+=h*wb.x; acc[5]+=h*wb.y; acc[6]+=h*wb.z; acc[7]+=h*wb.w;
        acc[8]+=h*wc.x; acc[9]+=h*wc.y; acc[10]+=h*wc.z; acc[11]+=h*wc.w;
    }
    #pragma unroll
    for (int t=0;t<NTASK;t++){
        for (int off=32; off>0; off>>=1) acc[t] += __shfl_down(acc[t], off);
    }
    if (lane==0){
        float* dst = (r < NG) ? &out[NG*NTASK + r*NTASK] : &out[(r-NG)*NTASK];
        #pragma unroll
        for (int t=0;t<NTASK;t++) dst[t] = acc[t] + bp2[t];
    }
}

extern "C" void kernel_launch(void* const* d_in, const int* in_sizes, int n_in,
                              void* d_out, int out_size, void* d_ws, size_t ws_size,
                              hipStream_t stream) {
    const float* x      = (const float*)d_in[0];
    const float* eattr  = (const float*)d_in[1];
    const int*   eidx   = (const int*)d_in[2];
    const int*   batch  = (const int*)d_in[3];
    const float* gumbel = (const float*)d_in[4];
    const int*   perm   = (const int*)d_in[5];
    const float* W_enc  = (const float*)d_in[6];
    const float* b_enc  = (const float*)d_in[7];
    const float* We_g   = (const float*)d_in[8];
    const float* be_g   = (const float*)d_in[9];
    const float* W1_g   = (const float*)d_in[10];
    const float* b1_g   = (const float*)d_in[11];
    const float* W2_g   = (const float*)d_in[12];
    const float* b2_g   = (const float*)d_in[13];
    const float* We_r   = (const float*)d_in[14];
    const float* be_r   = (const float*)d_in[15];
    const float* W1_r   = (const float*)d_in[16];
    const float* b1_r   = (const float*)d_in[17];
    const float* W2_r   = (const float*)d_in[18];
    const float* b2_r   = (const float*)d_in[19];
    const float* Wg1    = (const float*)d_in[20];
    const float* bg1    = (const float*)d_in[21];
    const float* Wg2    = (const float*)d_in[22];
    const float* bg2    = (const float*)d_in[23];
    const float* Wp1    = (const float*)d_in[24];
    const float* bp1    = (const float*)d_in[25];
    const float* Wp2    = (const float*)d_in[26];
    const float* bp2    = (const float*)d_in[27];
    float* out = (float*)d_out;

    const int* srcArr = eidx;
    const int* dstArr = eidx + NE;

    // ---- workspace (bump allocator, 256B aligned) ----
    char* w = (char*)d_ws;
    size_t off = 0;
    auto alloc = [&](size_t bytes)->char*{ char* p = w + off; off += (bytes + 255) & ~(size_t)255; return p; };
    bf16* xfeat = (bf16*)alloc((size_t)NN*SEM*2);
    bf16* cur_r = (bf16*)alloc((size_t)NN*SEM*2);
    bf16* cur_g = (bf16*)alloc((size_t)NN*SEM*2);
    bf16* apx   = (bf16*)alloc((size_t)NN*SEM*2);     // rationale-side agg out
    bf16* apx2  = (bf16*)alloc((size_t)NN*SEM*2);     // encoder-side agg out
    char* midc  = alloc((size_t)NN*SHID*2);           // mid_r; reused after trunk:
    bf16* mid_r = (bf16*)midc;
    bf16* Pbuf   = (bf16*)(midc + 12*1024*1024);
    bf16* hidP   = (bf16*)(midc + 20*1024*1024);
    bf16* mid_g = (bf16*)alloc((size_t)NN*SHID*2);
    bf16* wt1g  = (bf16*)alloc((size_t)5*HID*SEM*2);
    bf16* wt2g  = (bf16*)alloc((size_t)5*EMB*SHID*2);
    bf16* wt1r  = (bf16*)alloc((size_t)2*HID*SEM*2);
    bf16* wt2r  = (bf16*)alloc((size_t)2*EMB*SHID*2);
    bf16* wtg1  = (bf16*)alloc((size_t)HID*SEM*2);
    bf16* wtp1  = (bf16*)alloc((size_t)HID*SEM*2);
    float4* epack = (float4*)alloc((size_t)NE*16);
    float* gate  = (float*)alloc((size_t)NN*4);
    float* glogit= (float*)alloc((size_t)NN*2*4);
    float* hr    = (float*)alloc((size_t)NG*EMB*4);
    float* henv  = (float*)alloc((size_t)NG*EMB*4);
    bf16* hrb    = (bf16*)alloc((size_t)NG*SEM*2);
    bf16* henvb  = (bf16*)alloc((size_t)NG*SEM*2);
    float* rnum  = (float*)alloc(NG*4);
    float* cntf  = (float*)alloc(NG*4);
    float* na    = (float*)alloc(NG*4);
    float* ncv   = (float*)alloc(NG*4);
    float* pos   = (float*)alloc(NG*4);
    float* Ssum  = (float*)alloc(NG*4);
    int* deg     = (int*)alloc((size_t)NN*4);
    int* indptr  = (int*)alloc((size_t)(NN+1)*4);
    int* cursor  = (int*)alloc((size_t)NN*4);
    int* gstart  = (int*)alloc((size_t)(NG+1)*4);
    int* bsum    = (int*)alloc((size_t)NBLK_SCAN*4);
    int* boff    = (int*)alloc((size_t)NBLK_SCAN*4);

    const int NB_NE  = (NE+255)/256;
    const int NB_AG  = (NN*CG+255)/256;
    const int NB_GP  = (NG*SEM+255)/256;

    // ---- batched preamble: transposes + zeros + gstart + encoder, ONE dispatch ----
    dim3 gwp(19, 19, 18 + 98);
    k_wprep_all<<<gwp, 256, 0, stream>>>(W1_g, W2_g, W1_r, W2_r, Wg1, Wp1,
                                         wt1g, wt2g, wt1r, wt2r, wtg1, wtp1,
                                         deg, batch, gstart, x, W_enc, b_enc, xfeat, glogit);

    // ---- CSR build + fused scatter/edge-pack ----
    k_hist       <<<NB_NE, 256, 0, stream>>>(dstArr, deg);
    k_scanA      <<<NBLK_SCAN, 256, 0, stream>>>(deg, bsum);
    k_scanB      <<<1, 128, 0, stream>>>(bsum, boff);
    k_scanC      <<<NBLK_SCAN, 256, 0, stream>>>(deg, boff, indptr, cursor);
    k_scatterprep<<<NB_NE, 256, 0, stream>>>(dstArr, srcArr, eattr, cursor, epack);

    dim3 gm1z((HID+127)/128, (NN+127)/128, 2);   // N=600 pairs: (5,235,2)
    dim3 gm160z(2, (NN+127)/128, 2);             // N=300 BN160 pairs: (2,235,2)

    // ---- layer 0 (both stacks): shared-gather dual agg, then paired GEMMs ----
    k_agg4d<<<NB_AG, 256, 0, stream>>>(xfeat, We_r, be_r, We_g, be_g, epack, indptr, apx, apx2);
    k_gemm2z<<<gm1z, 256, 0, stream>>>(apx, apx2, wt1r, wt1g, b1_r, b1_g,
                                       nullptr, nullptr, mid_r, mid_g, NN, HID, SEM, SHID, 1, 1);
    k_gemm160z<<<gm160z, 256, 0, stream>>>(mid_r, mid_g, wt2r, wt2g, b2_r, b2_g,
                                           xfeat, xfeat, cur_r, cur_g, NN, EMB, SHID, SEM, 1, 1);

    // ---- layer 1 (both stacks): dual-SOURCE agg (one epack pass) + paired GEMMs ----
    k_agg4dd<<<NB_AG, 256, 0, stream>>>(cur_r, cur_g, We_r + 3*EMB, be_r + EMB,
                                        We_g + 3*EMB, be_g + EMB, epack, indptr, apx, apx2);
    k_gemm2z<<<gm1z, 256, 0, stream>>>(apx, apx2, wt1r + (size_t)HID*SEM, wt1g + (size_t)HID*SEM,
                                       b1_r + HID, b1_g + HID, nullptr, nullptr, mid_r, mid_g,
                                       NN, HID, SEM, SHID, 1, 1);
    k_gemm160z<<<gm160z, 256, 0, stream>>>(mid_r, mid_g, wt2r + (size_t)EMB*SHID, wt2g + (size_t)EMB*SHID,
                                           b2_r + EMB, b2_g + EMB, cur_r, cur_g, cur_r, cur_g,
                                           NN, EMB, SHID, SEM, 0, 1);   // rationale last layer: no relu

    // ---- encoder layer 2 agg; (gate-gemm -> logits) paired with enc-l2 g1; g2+gatefin fused ----
    k_agg4 <<<NB_AG, 256, 0, stream>>>(cur_g, We_g + 2*3*EMB, be_g + 2*EMB, epack, indptr, apx2);
    k_gatepair<<<2350, 256, 0, stream>>>(cur_r, wtg1, bg1, Wg2, glogit,
                                         apx2, wt1g + (size_t)2*HID*SEM, b1_g + 2*HID, mid_g);
    k_g160gate<<<588, 256, 0, stream>>>(mid_g, wt2g + (size_t)2*EMB*SHID, b2_g + 2*EMB, cur_g, cur_g,
                                        glogit, bg2, gumbel, gate);

    // ---- encoder layers 3,4: row-split GEMM pipeline (g1_lo -> g1_hi∥g160_lo -> g160_hi) ----
    for (int l=3; l<5; l++){
        const bf16* w1 = wt1g + (size_t)l*HID*SEM;
        const float* b1 = b1_g + l*HID;
        const bf16* w2 = wt2g + (size_t)l*EMB*SHID;
        const float* b2 = b2_g + l*EMB;
        int relu2 = (l<4) ? 1 : 0;
        k_agg4<<<NB_AG, 256, 0, stream>>>(cur_g, We_g + l*3*EMB, be_g + l*EMB, epack, indptr, apx2);
        // g1 rows [0, MS)
        k_gemm2<<<dim3(5, 118), 256, 0, stream>>>(apx2, w1, b1, nullptr, mid_g, NN, HID, SEM, SHID, 1);
        // g1 rows [MS, NN) || g160 rows [0, MS)
        k_g1g160<<<821, 256, 0, stream>>>(apx2, w1, b1, mid_g,
                                          mid_g, w2, b2, cur_g, cur_g, relu2);
        // g160 rows [MS, NN)
        k_gemm160<<<dim3(2, 117), 256, 0, stream>>>(mid_g, w2, b2, cur_g, cur_g,
                                                    NN, EMB, SHID, SEM, relu2, MS);
    }
    // cur_g now holds h_node (bf16, stride SEM)

    // ---- fused pooling + mean + norms ----
    k_poolmean<<<NG, 320, 0, stream>>>(cur_g, gate, gstart, hr, henv, hrb, henvb, Pbuf,
                                       na, ncv, pos, rnum, cntf, Ssum);
    k_pbuild2 <<<NB_GP, 256, 0, stream>>>(hr, henv, perm, Pbuf);
    // ---- contrastive sim rowsums + head GEMM in one fat dispatch ----
    dim3 gsh(12, 24, 2);
    k_simhead<<<gsh, 256, 0, stream>>>(hrb, henvb, na, ncv, Ssum, Pbuf, wtp1, bp1, hidP);
    // ---- pred + loss fused ----
    k_predloss<<<751, 256, 0, stream>>>(hidP, Wp2, bp2, cntf, rnum, pos, Ssum, out);
}

// Round 9
// 848.386 us; speedup vs baseline: 1.0387x; 1.0387x over previous
//
#include <hip/hip_runtime.h>
#include <hip/hip_bf16.h>

typedef __hip_bfloat16 bf16;
typedef __attribute__((ext_vector_type(8))) short bf16x8;
typedef __attribute__((ext_vector_type(4))) float f32x4;

#define NN 30000      // nodes
#define NE 240000     // edges
#define NG 1500       // graphs
#define EMB 300
#define HID 600
#define NTASK 12
#define SEM 320       // padded stride for EMB-dim tensors
#define SHID 608      // padded stride for HID-dim tensors
#define CG 75         // 4-channel groups — 75 thr/node: best TLP (round-9 lesson)
#define NBLK_SCAN 118 // (NN+255)/256

__device__ __forceinline__ float tof(bf16 v){ return __bfloat162float(v); }
__device__ __forceinline__ bf16  tob(float v){ return __float2bfloat16(v); }
__device__ __forceinline__ float b2f(unsigned short u){ return __uint_as_float(((unsigned)u)<<16); }

// bijective XCD-aware block swizzle (m204): dispatch slot orig lands on XCD orig%8 (RR);
// give each XCD a CONTIGUOUS tile range so column-tiles sharing an A row-panel hit one L2.
__device__ __forceinline__ int xcd_swz(int orig, int nwg){
    int q = nwg >> 3, r = nwg & 7;
    int x = orig & 7, w = orig >> 3;
    return (x < r ? x*(q+1) : r*(q+1) + (x-r)*q) + w;
}

// ---------------- CSR build (by dst) ----------------
__global__ __launch_bounds__(256) void k_hist(const int* __restrict__ dst, int* __restrict__ deg){
    int e = blockIdx.x*256 + threadIdx.x;
    if (e < NE) atomicAdd(&deg[dst[e]], 1);
}

__global__ __launch_bounds__(256) void k_scanA(const int* __restrict__ deg, int* __restrict__ bsum){
    __shared__ int red[256];
    int b = blockIdx.x, t = threadIdx.x;
    int i = b*256 + t;
    red[t] = (i < NN) ? deg[i] : 0;
    __syncthreads();
    for (int off=128; off>0; off>>=1){ if (t<off) red[t]+=red[t+off]; __syncthreads(); }
    if (t==0) bsum[b] = red[0];
}

__global__ __launch_bounds__(128) void k_scanB(const int* __restrict__ bsum, int* __restrict__ boff){
    __shared__ int s[128];
    int t = threadIdx.x;
    int v = (t < NBLK_SCAN) ? bsum[t] : 0;
    s[t] = v;
    __syncthreads();
    for (int off=1; off<128; off<<=1){
        int add = (t>=off) ? s[t-off] : 0;
        __syncthreads();
        s[t] += add;
        __syncthreads();
    }
    if (t < NBLK_SCAN) boff[t] = s[t] - v;   // exclusive
}

__global__ __launch_bounds__(256) void k_scanC(const int* __restrict__ deg, const int* __restrict__ boff,
                                               int* __restrict__ indptr, int* __restrict__ cursor){
    __shared__ int s[256];
    int b = blockIdx.x, t = threadIdx.x;
    int i = b*256 + t;
    int v = (i < NN) ? deg[i] : 0;
    s[t] = v;
    __syncthreads();
    for (int off=1; off<256; off<<=1){
        int add = (t>=off) ? s[t-off] : 0;
        __syncthreads();
        s[t] += add;
        __syncthreads();
    }
    int excl = s[t] - v + boff[b];
    if (i < NN){ indptr[i] = excl; cursor[i] = excl; }
    if (i == 0) indptr[NN] = NE;
}

// scatter + edge pack fused: write epack directly at the atomic cursor slot (no eid pass)
__global__ __launch_bounds__(256) void k_scatterprep(const int* __restrict__ dst, const int* __restrict__ src,
                      const float* __restrict__ eattr, int* __restrict__ cursor, float4* __restrict__ epack){
    int e = blockIdx.x*256 + threadIdx.x;
    if (e >= NE) return;
    int p = atomicAdd(&cursor[dst[e]], 1);
    float4 q;
    q.x = __int_as_float(src[e]);
    q.y = eattr[e*3]; q.z = eattr[e*3+1]; q.w = eattr[e*3+2];
    epack[p] = q;
}

// ---------------- batched preamble: weight transposes + zeros + gstart + node encoder ----------------
// z: 0..4 W1_g | 5..9 W2_g | 10..11 W1_r | 12..13 W2_r | 14 Wg1 | 15 Wp1 | 16 zero deg+glogit | 17 gstart
// z >= 18: node encoder slices
__global__ __launch_bounds__(256) void k_wprep_all(
        const float* __restrict__ W1_g, const float* __restrict__ W2_g,
        const float* __restrict__ W1_r, const float* __restrict__ W2_r,
        const float* __restrict__ Wg1,  const float* __restrict__ Wp1,
        bf16* __restrict__ wt1g, bf16* __restrict__ wt2g,
        bf16* __restrict__ wt1r, bf16* __restrict__ wt2r,
        bf16* __restrict__ wtg1, bf16* __restrict__ wtp1,
        int* __restrict__ deg, const int* __restrict__ batch, int* __restrict__ gstart,
        const float* __restrict__ x, const float* __restrict__ W_enc,
        const float* __restrict__ b_enc, bf16* __restrict__ xfeat,
        float* __restrict__ glogit){
    __shared__ float t[32][33];
    int z = blockIdx.z;
    if (z >= 18){
        int idx = ((z-18)*361 + blockIdx.y*19 + blockIdx.x)*256 + threadIdx.x;
        if (idx >= NN*EMB) return;
        int n = idx / EMB, c = idx - n*EMB;
        float acc = b_enc[c];
        #pragma unroll
        for (int k=0;k<9;k++) acc += x[n*9+k] * W_enc[k*EMB+c];
        xfeat[(size_t)n*SEM + c] = tob(acc);
        return;
    }
    if (z == 16){
        int i = (blockIdx.y*19 + blockIdx.x)*256 + threadIdx.x;
        if (i < NN){ deg[i] = 0; glogit[2*i] = 0.f; glogit[2*i+1] = 0.f; }
        return;
    }
    if (z == 17){
        int g = (blockIdx.y*19 + blockIdx.x)*256 + threadIdx.x;
        if (g > NG) return;
        if (g == NG){ gstart[NG] = NN; return; }
        int lo=0, hi=NN;
        while (lo<hi){ int mid=(lo+hi)>>1; if (batch[mid] < g) lo=mid+1; else hi=mid; }
        gstart[g] = lo;
        return;
    }
    const float* Ws; bf16* Wd; int K, Kp, N;
    if (z < 5)      { Ws = W1_g + (size_t)z*EMB*HID;      Wd = wt1g + (size_t)z*HID*SEM;      K=EMB; Kp=SEM;  N=HID; }
    else if (z < 10){ int l=z-5;  Ws = W2_g + (size_t)l*HID*EMB; Wd = wt2g + (size_t)l*EMB*SHID; K=HID; Kp=SHID; N=EMB; }
    else if (z < 12){ int l=z-10; Ws = W1_r + (size_t)l*EMB*HID; Wd = wt1r + (size_t)l*HID*SEM;  K=EMB; Kp=SEM;  N=HID; }
    else if (z < 14){ int l=z-12; Ws = W2_r + (size_t)l*HID*EMB; Wd = wt2r + (size_t)l*EMB*SHID; K=HID; Kp=SHID; N=EMB; }
    else if (z ==14){ Ws = Wg1; Wd = wtg1; K=EMB; Kp=SEM; N=HID; }
    else            { Ws = Wp1; Wd = wtp1; K=EMB; Kp=SEM; N=HID; }
    int n0 = blockIdx.x*32, k0 = blockIdx.y*32;
    if (n0 >= N || k0 >= Kp) return;
    int tx = threadIdx.x & 31, ty = threadIdx.x >> 5;
    #pragma unroll
    for (int i=0;i<4;i++){
        int k = k0 + ty + i*8, n = n0 + tx;
        t[ty+i*8][tx] = (k<K && n<N) ? Ws[(size_t)k*N+n] : 0.f;
    }
    __syncthreads();
    #pragma unroll
    for (int i=0;i<4;i++){
        int n = n0 + ty + i*8, k = k0 + tx;
        if (n<N && k<Kp) Wd[(size_t)n*Kp+k] = tob(t[tx][ty+i*8]);
    }
}

// ---------------- agg body (device): thread=(node, 4-ch group), 2-deep pipeline ----------------
__device__ __forceinline__ void agg4_body(const bf16* __restrict__ cur, const float* __restrict__ We,
                      const float* __restrict__ be, const float4* __restrict__ epack,
                      const int* __restrict__ indptr, bf16* __restrict__ apx, int idx){
    int n = idx / CG, cg = idx - n*CG;
    int c0 = cg*4;
    float w0[4], w1[4], w2[4], bbv[4], acc[4];
    #pragma unroll
    for (int j=0;j<4;j++){
        w0[j] = We[c0+j]; w1[j] = We[EMB+c0+j]; w2[j] = We[2*EMB+c0+j]; bbv[j] = be[c0+j];
    }
    ushort4 hs = *(const ushort4*)&cur[(size_t)n*SEM + c0];
    acc[0]=b2f(hs.x); acc[1]=b2f(hs.y); acc[2]=b2f(hs.z); acc[3]=b2f(hs.w);
    int k  = indptr[n], k1 = indptr[n+1];

    auto accum4 = [&](float4 e0, float4 e1, float4 e2, float4 e3,
                      ushort4 ha, ushort4 hb, ushort4 hc, ushort4 hd){
        float fa[4] = {b2f(ha.x), b2f(ha.y), b2f(ha.z), b2f(ha.w)};
        float fb[4] = {b2f(hb.x), b2f(hb.y), b2f(hb.z), b2f(hb.w)};
        float fc[4] = {b2f(hc.x), b2f(hc.y), b2f(hc.z), b2f(hc.w)};
        float fd[4] = {b2f(hd.x), b2f(hd.y), b2f(hd.z), b2f(hd.w)};
        #pragma unroll
        for (int j=0;j<4;j++){
            float va = fa[j] + e0.y*w0[j] + e0.z*w1[j] + e0.w*w2[j] + bbv[j];
            float vb = fb[j] + e1.y*w0[j] + e1.z*w1[j] + e1.w*w2[j] + bbv[j];
            float vc = fc[j] + e2.y*w0[j] + e2.z*w1[j] + e2.w*w2[j] + bbv[j];
            float vd = fd[j] + e3.y*w0[j] + e3.z*w1[j] + e3.w*w2[j] + bbv[j];
            acc[j] += fmaxf(va, 0.f) + fmaxf(vb, 0.f) + fmaxf(vc, 0.f) + fmaxf(vd, 0.f);
        }
    };

    if (k + 4 <= k1){
        float4 e0 = epack[k], e1 = epack[k+1], e2 = epack[k+2], e3 = epack[k+3];
        ushort4 h0 = *(const ushort4*)&cur[(size_t)__float_as_int(e0.x)*SEM + c0];
        ushort4 h1 = *(const ushort4*)&cur[(size_t)__float_as_int(e1.x)*SEM + c0];
        ushort4 h2 = *(const ushort4*)&cur[(size_t)__float_as_int(e2.x)*SEM + c0];
        ushort4 h3 = *(const ushort4*)&cur[(size_t)__float_as_int(e3.x)*SEM + c0];
        while (k + 8 <= k1){
            float4 f0 = epack[k+4], f1 = epack[k+5], f2 = epack[k+6], f3 = epack[k+7];
            ushort4 g0 = *(const ushort4*)&cur[(size_t)__float_as_int(f0.x)*SEM + c0];
            ushort4 g1 = *(const ushort4*)&cur[(size_t)__float_as_int(f1.x)*SEM + c0];
            ushort4 g2 = *(const ushort4*)&cur[(size_t)__float_as_int(f2.x)*SEM + c0];
            ushort4 g3 = *(const ushort4*)&cur[(size_t)__float_as_int(f3.x)*SEM + c0];
            accum4(e0,e1,e2,e3, h0,h1,h2,h3);
            e0=f0; e1=f1; e2=f2; e3=f3;
            h0=g0; h1=g1; h2=g2; h3=g3;
            k += 4;
        }
        accum4(e0,e1,e2,e3, h0,h1,h2,h3);
        k += 4;
    }
    for (; k < k1; k++){
        float4 e0 = epack[k];
        int s0 = __float_as_int(e0.x);
        ushort4 ha = *(const ushort4*)&cur[(size_t)s0*SEM + c0];
        float fa[4] = {b2f(ha.x), b2f(ha.y), b2f(ha.z), b2f(ha.w)};
        #pragma unroll
        for (int j=0;j<4;j++){
            float va = fa[j] + e0.y*w0[j] + e0.z*w1[j] + e0.w*w2[j] + bbv[j];
            acc[j] += fmaxf(va, 0.f);
        }
    }
    ushort4 o;
    o.x = __bfloat16_as_ushort(tob(acc[0]));
    o.y = __bfloat16_as_ushort(tob(acc[1]));
    o.z = __bfloat16_as_ushort(tob(acc[2]));
    o.w = __bfloat16_as_ushort(tob(acc[3]));
    *(ushort4*)&apx[(size_t)n*SEM + c0] = o;
}

__global__ __launch_bounds__(256) void k_agg4(const bf16* __restrict__ cur, const float* __restrict__ We,
                      const float* __restrict__ be, const float4* __restrict__ epack,
                      const int* __restrict__ indptr, bf16* __restrict__ apx){
    int idx = blockIdx.x*256 + threadIdx.x;
    if (idx >= NN*CG) return;
    agg4_body(cur, We, be, epack, indptr, apx, idx);
}

// ---------------- dual agg: one gather pass feeds BOTH weight sets (layer-0 fusion) ----------------
__global__ __launch_bounds__(256) void k_agg4d(const bf16* __restrict__ cur,
                      const float* __restrict__ WeA, const float* __restrict__ beA,
                      const float* __restrict__ WeB, const float* __restrict__ beB,
                      const float4* __restrict__ epack, const int* __restrict__ indptr,
                      bf16* __restrict__ apxA, bf16* __restrict__ apxB){
    int idx = blockIdx.x*256 + threadIdx.x;
    if (idx >= NN*CG) return;
    int n = idx / CG, cg = idx - n*CG;
    int c0 = cg*4;
    float a0[4], a1[4], a2[4], ab[4], accA[4];
    float b0[4], b1[4], b2[4], bb[4], accB[4];
    #pragma unroll
    for (int j=0;j<4;j++){
        a0[j]=WeA[c0+j]; a1[j]=WeA[EMB+c0+j]; a2[j]=WeA[2*EMB+c0+j]; ab[j]=beA[c0+j];
        b0[j]=WeB[c0+j]; b1[j]=WeB[EMB+c0+j]; b2[j]=WeB[2*EMB+c0+j]; bb[j]=beB[c0+j];
    }
    ushort4 hs = *(const ushort4*)&cur[(size_t)n*SEM + c0];
    float fs[4] = {b2f(hs.x), b2f(hs.y), b2f(hs.z), b2f(hs.w)};
    #pragma unroll
    for (int j=0;j<4;j++){ accA[j]=fs[j]; accB[j]=fs[j]; }
    int k = indptr[n], k1 = indptr[n+1];
    for (; k+2 <= k1; k += 2){
        float4 e0 = epack[k], e1 = epack[k+1];
        int s0 = __float_as_int(e0.x), s1 = __float_as_int(e1.x);
        ushort4 ha = *(const ushort4*)&cur[(size_t)s0*SEM + c0];
        ushort4 hb = *(const ushort4*)&cur[(size_t)s1*SEM + c0];
        float fa[4] = {b2f(ha.x), b2f(ha.y), b2f(ha.z), b2f(ha.w)};
        float fb[4] = {b2f(hb.x), b2f(hb.y), b2f(hb.z), b2f(hb.w)};
        #pragma unroll
        for (int j=0;j<4;j++){
            accA[j] += fmaxf(fa[j] + e0.y*a0[j] + e0.z*a1[j] + e0.w*a2[j] + ab[j], 0.f)
                     + fmaxf(fb[j] + e1.y*a0[j] + e1.z*a1[j] + e1.w*a2[j] + ab[j], 0.f);
            accB[j] += fmaxf(fa[j] + e0.y*b0[j] + e0.z*b1[j] + e0.w*b2[j] + bb[j], 0.f)
                     + fmaxf(fb[j] + e1.y*b0[j] + e1.z*b1[j] + e1.w*b2[j] + bb[j], 0.f);
        }
    }
    if (k < k1){
        float4 e0 = epack[k];
        int s0 = __float_as_int(e0.x);
        ushort4 ha = *(const ushort4*)&cur[(size_t)s0*SEM + c0];
        float fa[4] = {b2f(ha.x), b2f(ha.y), b2f(ha.z), b2f(ha.w)};
        #pragma unroll
        for (int j=0;j<4;j++){
            accA[j] += fmaxf(fa[j] + e0.y*a0[j] + e0.z*a1[j] + e0.w*a2[j] + ab[j], 0.f);
            accB[j] += fmaxf(fa[j] + e0.y*b0[j] + e0.z*b1[j] + e0.w*b2[j] + bb[j], 0.f);
        }
    }
    ushort4 oA, oB;
    oA.x=__bfloat16_as_ushort(tob(accA[0])); oA.y=__bfloat16_as_ushort(tob(accA[1]));
    oA.z=__bfloat16_as_ushort(tob(accA[2])); oA.w=__bfloat16_as_ushort(tob(accA[3]));
    oB.x=__bfloat16_as_ushort(tob(accB[0])); oB.y=__bfloat16_as_ushort(tob(accB[1]));
    oB.z=__bfloat16_as_ushort(tob(accB[2])); oB.w=__bfloat16_as_ushort(tob(accB[3]));
    *(ushort4*)&apxA[(size_t)n*SEM + c0] = oA;
    *(ushort4*)&apxB[(size_t)n*SEM + c0] = oB;
}

// ---------------- dual-SOURCE agg (layer 1): one epack pass gathers from BOTH residual streams ----
// replaces the z-paired form: halves epack loads + address math; round-8 win (88 -> 72 us)
__global__ __launch_bounds__(256) void k_agg4dd(const bf16* __restrict__ curA, const bf16* __restrict__ curB,
                      const float* __restrict__ WeA, const float* __restrict__ beA,
                      const float* __restrict__ WeB, const float* __restrict__ beB,
                      const float4* __restrict__ epack, const int* __restrict__ indptr,
                      bf16* __restrict__ apxA, bf16* __restrict__ apxB){
    int idx = blockIdx.x*256 + threadIdx.x;
    if (idx >= NN*CG) return;
    int n = idx / CG, cg = idx - n*CG;
    int c0 = cg*4;
    float a0[4], a1[4], a2[4], ab[4], accA[4];
    float b0[4], b1[4], b2[4], bb[4], accB[4];
    #pragma unroll
    for (int j=0;j<4;j++){
        a0[j]=WeA[c0+j]; a1[j]=WeA[EMB+c0+j]; a2[j]=WeA[2*EMB+c0+j]; ab[j]=beA[c0+j];
        b0[j]=WeB[c0+j]; b1[j]=WeB[EMB+c0+j]; b2[j]=WeB[2*EMB+c0+j]; bb[j]=beB[c0+j];
    }
    ushort4 hsA = *(const ushort4*)&curA[(size_t)n*SEM + c0];
    ushort4 hsB = *(const ushort4*)&curB[(size_t)n*SEM + c0];
    accA[0]=b2f(hsA.x); accA[1]=b2f(hsA.y); accA[2]=b2f(hsA.z); accA[3]=b2f(hsA.w);
    accB[0]=b2f(hsB.x); accB[1]=b2f(hsB.y); accB[2]=b2f(hsB.z); accB[3]=b2f(hsB.w);
    int k = indptr[n], k1 = indptr[n+1];
    for (; k+2 <= k1; k += 2){
        float4 e0 = epack[k], e1 = epack[k+1];
        int s0 = __float_as_int(e0.x), s1 = __float_as_int(e1.x);
        ushort4 ha = *(const ushort4*)&curA[(size_t)s0*SEM + c0];
        ushort4 hb = *(const ushort4*)&curA[(size_t)s1*SEM + c0];
        ushort4 hc = *(const ushort4*)&curB[(size_t)s0*SEM + c0];
        ushort4 hd = *(const ushort4*)&curB[(size_t)s1*SEM + c0];
        float fa[4] = {b2f(ha.x), b2f(ha.y), b2f(ha.z), b2f(ha.w)};
        float fb[4] = {b2f(hb.x), b2f(hb.y), b2f(hb.z), b2f(hb.w)};
        float fc[4] = {b2f(hc.x), b2f(hc.y), b2f(hc.z), b2f(hc.w)};
        float fd[4] = {b2f(hd.x), b2f(hd.y), b2f(hd.z), b2f(hd.w)};
        #pragma unroll
        for (int j=0;j<4;j++){
            accA[j] += fmaxf(fa[j] + e0.y*a0[j] + e0.z*a1[j] + e0.w*a2[j] + ab[j], 0.f)
                     + fmaxf(fb[j] + e1.y*a0[j] + e1.z*a1[j] + e1.w*a2[j] + ab[j], 0.f);
            accB[j] += fmaxf(fc[j] + e0.y*b0[j] + e0.z*b1[j] + e0.w*b2[j] + bb[j], 0.f)
                     + fmaxf(fd[j] + e1.y*b0[j] + e1.z*b1[j] + e1.w*b2[j] + bb[j], 0.f);
        }
    }
    if (k < k1){
        float4 e0 = epack[k];
        int s0 = __float_as_int(e0.x);
        ushort4 ha = *(const ushort4*)&curA[(size_t)s0*SEM + c0];
        ushort4 hc = *(const ushort4*)&curB[(size_t)s0*SEM + c0];
        float fa[4] = {b2f(ha.x), b2f(ha.y), b2f(ha.z), b2f(ha.w)};
        float fc[4] = {b2f(hc.x), b2f(hc.y), b2f(hc.z), b2f(hc.w)};
        #pragma unroll
        for (int j=0;j<4;j++){
            accA[j] += fmaxf(fa[j] + e0.y*a0[j] + e0.z*a1[j] + e0.w*a2[j] + ab[j], 0.f);
            accB[j] += fmaxf(fc[j] + e0.y*b0[j] + e0.z*b1[j] + e0.w*b2[j] + bb[j], 0.f);
        }
    }
    ushort4 oA, oB;
    oA.x=__bfloat16_as_ushort(tob(accA[0])); oA.y=__bfloat16_as_ushort(tob(accA[1]));
    oA.z=__bfloat16_as_ushort(tob(accA[2])); oA.w=__bfloat16_as_ushort(tob(accA[3]));
    oB.x=__bfloat16_as_ushort(tob(accB[0])); oB.y=__bfloat16_as_ushort(tob(accB[1]));
    oB.z=__bfloat16_as_ushort(tob(accB[2])); oB.w=__bfloat16_as_ushort(tob(accB[3]));
    *(ushort4*)&apxA[(size_t)n*SEM + c0] = oA;
    *(ushort4*)&apxB[(size_t)n*SEM + c0] = oB;
}

// ---------------- MFMA bf16 GEMM body (BN=128): reg-staged dbuf K-loop ----------------
// Reg-staging (not global_load_lds): register loads stay in flight across the barrier (round-1
// lesson). Used for N=600 GEMMs, gatepair, simhead.
__device__ __forceinline__ void gemm_body(const bf16* __restrict__ A, const bf16* __restrict__ Bt,
        const float* __restrict__ bias, const bf16* __restrict__ R, bf16* __restrict__ C,
        int M, int N, int Kp, int ldc, int relu_out, short* lds, int m0, int n0){
    short* Ct = lds;
    const int CS = 136;
    int tid = threadIdx.x;
    int wave = tid >> 6, lane = tid & 63;
    int wm = wave >> 1, wn = wave & 1;

    int srow = tid >> 1;
    int sq   = (tid & 1) * 2;
    int grA = min(m0 + srow, M-1);
    int grB = min(n0 + srow, N-1);
    const bf16* pA = A  + (size_t)grA*Kp + sq*8;
    const bf16* pB = Bt + (size_t)grB*Kp + sq*8;
    int aoff0 = ((srow>>4)*64 +  sq   *16 + (srow&15))*8;
    int aoff1 = ((srow>>4)*64 + (sq+1)*16 + (srow&15))*8;

    f32x4 acc[4][4];
    #pragma unroll
    for (int i=0;i<4;i++){
        #pragma unroll
        for (int j=0;j<4;j++) acc[i][j] = (f32x4){0.f,0.f,0.f,0.f};
    }

    int KC = Kp >> 5;
    uint4 ra0 = *(const uint4*)(pA);
    uint4 ra1 = *(const uint4*)(pA + 8);
    uint4 rb0 = *(const uint4*)(pB);
    uint4 rb1 = *(const uint4*)(pB + 8);
    *(uint4*)(lds + aoff0)        = ra0;
    *(uint4*)(lds + aoff1)        = ra1;
    *(uint4*)(lds + 4096 + aoff0) = rb0;
    *(uint4*)(lds + 4096 + aoff1) = rb1;
    __syncthreads();
    if (KC > 1){
        ra0 = *(const uint4*)(pA + 32); ra1 = *(const uint4*)(pA + 40);
        rb0 = *(const uint4*)(pB + 32); rb1 = *(const uint4*)(pB + 40);
    }

    for (int kc=0; kc<KC; ++kc){
        short* cbuf = lds + (kc & 1)*8192;
        short* nbuf = lds + ((kc+1) & 1)*8192;
        if (kc+1 < KC){
            *(uint4*)(nbuf + aoff0)        = ra0;
            *(uint4*)(nbuf + aoff1)        = ra1;
            *(uint4*)(nbuf + 4096 + aoff0) = rb0;
            *(uint4*)(nbuf + 4096 + aoff1) = rb1;
            if (kc+2 < KC){
                const bf16* qA = pA + (kc+2)*32;
                const bf16* qB = pB + (kc+2)*32;
                ra0 = *(const uint4*)(qA); ra1 = *(const uint4*)(qA+8);
                rb0 = *(const uint4*)(qB); rb1 = *(const uint4*)(qB+8);
            }
        }
        bf16x8 af[4], bfr[4];
        #pragma unroll
        for (int i=0;i<4;i++) af[i]  = *(const bf16x8*)(cbuf + ((wm*4+i)*64 + lane)*8);
        #pragma unroll
        for (int j=0;j<4;j++) bfr[j] = *(const bf16x8*)(cbuf + 4096 + ((wn*4+j)*64 + lane)*8);
        #pragma unroll
        for (int i=0;i<4;i++){
            #pragma unroll
            for (int j=0;j<4;j++)
                acc[i][j] = __builtin_amdgcn_mfma_f32_16x16x32_bf16(af[i], bfr[j], acc[i][j], 0, 0, 0);
        }
        __syncthreads();
    }

    int lq = lane >> 4, lr = lane & 15;
    #pragma unroll
    for (int i=0;i<4;i++){
        int rl = (wm*4+i)*16 + lq*4;
        #pragma unroll
        for (int j=0;j<4;j++){
            int cl = (wn*4+j)*16 + lr;
            float bv = bias[min(n0+cl, N-1)];
            #pragma unroll
            for (int r=0;r<4;r++){
                float v = acc[i][j][r] + bv;
                if (relu_out) v = fmaxf(v, 0.f);
                Ct[(rl+r)*CS + cl] = (short)__bfloat16_as_ushort(tob(v));
            }
        }
    }
    __syncthreads();
    #pragma unroll
    for (int p=0;p<8;p++){
        int rl = p*16 + (tid>>4);
        int cl = (tid&15)*8;
        int row = m0 + rl, col = n0 + cl;
        if (row < M && col < N){
            union { short s8[8]; uint4 v; } u;
            u.v = *(uint4*)&Ct[rl*CS + cl];
            if (R){
                const bf16* rp = &R[(size_t)row*ldc + col];
                #pragma unroll
                for (int e=0;e<8;e++){
                    float v = b2f((unsigned short)u.s8[e]) + tof(rp[e]);
                    u.s8[e] = (short)__bfloat16_as_ushort(tob(v));
                }
            }
            *(uint4*)&C[(size_t)row*ldc + col] = u.v;
        }
    }
}

__global__ __launch_bounds__(256) void k_gemm2(const bf16* __restrict__ A, const bf16* __restrict__ Bt,
        const float* __restrict__ bias, const bf16* __restrict__ R, bf16* __restrict__ C,
        int M, int N, int Kp, int ldc, int relu_out){
    __shared__ __align__(16) char ldsbuf[34816];
    int nwg = gridDim.x*gridDim.y;
    int w = xcd_swz(blockIdx.y*gridDim.x + blockIdx.x, nwg);
    gemm_body(A, Bt, bias, R, C, M, N, Kp, ldc, relu_out, (short*)ldsbuf,
              (w/gridDim.x)*128, (w%gridDim.x)*128);
}

__global__ __launch_bounds__(256) void k_gemm2z(
        const bf16* __restrict__ A0, const bf16* __restrict__ A1,
        const bf16* __restrict__ Bt0, const bf16* __restrict__ Bt1,
        const float* __restrict__ bias0, const float* __restrict__ bias1,
        const bf16* __restrict__ R0, const bf16* __restrict__ R1,
        bf16* __restrict__ C0, bf16* __restrict__ C1,
        int M, int N, int Kp, int ldc, int relu0, int relu1){
    __shared__ __align__(16) char ldsbuf[34816];
    int nwg = gridDim.x*gridDim.y;
    int w = xcd_swz(blockIdx.y*gridDim.x + blockIdx.x, nwg);
    int m0 = (w/gridDim.x)*128, n0 = (w%gridDim.x)*128;
    if (blockIdx.z == 0) gemm_body(A0, Bt0, bias0, R0, C0, M, N, Kp, ldc, relu0, (short*)ldsbuf, m0, n0);
    else                 gemm_body(A1, Bt1, bias1, R1, C1, M, N, Kp, ldc, relu1, (short*)ldsbuf, m0, n0);
}

// ---------------- BN=160 GEMM body: for N=300 outputs ----------------
// vs BN=128 (3 col-tiles, 384 cols): 2 col-tiles -> A re-fetched 2x not 3x AND cols 320 not 384.
// LDS per buffer: A 4096 + B 5120 shorts (stride 9216 shorts); Ct 128x168 = 43008 B total.
__device__ __forceinline__ void gemm160_body(const bf16* __restrict__ A, const bf16* __restrict__ Bt,
        const float* __restrict__ bias, const bf16* __restrict__ R, bf16* __restrict__ C,
        int M, int N, int Kp, int ldc, int relu_out, short* lds, int m0, int n0){
    short* Ct = lds;
    const int CS = 168;
    const int BUF = 9216;   // shorts per dbuf half
    int tid = threadIdx.x;
    int wave = tid >> 6, lane = tid & 63;
    int wm = wave >> 1, wn = wave & 1;

    // A staging: 512 16B chunks, 2/thread
    int srow = tid >> 1;
    int sq   = (tid & 1) * 2;
    int grA = min(m0 + srow, M-1);
    const bf16* pA = A + (size_t)grA*Kp + sq*8;
    int aoff0 = ((srow>>4)*64 +  sq   *16 + (srow&15))*8;
    int aoff1 = ((srow>>4)*64 + (sq+1)*16 + (srow&15))*8;

    // B staging: 640 16B chunks: tid, tid+256, and tid+512 for tid<128 (wave-uniform split)
    int cB0 = tid, cB1 = tid + 256, cB2 = tid + 512;
    int br0 = cB0>>2, bq0 = cB0&3;
    int br1 = cB1>>2, bq1 = cB1&3;
    int br2 = cB2>>2, bq2 = cB2&3;
    const bf16* pB0 = Bt + (size_t)min(n0+br0, N-1)*Kp + bq0*8;
    const bf16* pB1 = Bt + (size_t)min(n0+br1, N-1)*Kp + bq1*8;
    const bf16* pB2 = Bt + (size_t)min(n0+br2, N-1)*Kp + bq2*8;
    int boff0 = 4096 + ((br0>>4)*64 + bq0*16 + (br0&15))*8;
    int boff1 = 4096 + ((br1>>4)*64 + bq1*16 + (br1&15))*8;
    int boff2 = 4096 + ((br2>>4)*64 + bq2*16 + (br2&15))*8;
    bool b3 = (tid < 128);

    f32x4 acc[4][5];
    #pragma unroll
    for (int i=0;i<4;i++){
        #pragma unroll
        for (int j=0;j<5;j++) acc[i][j] = (f32x4){0.f,0.f,0.f,0.f};
    }

    int KC = Kp >> 5;
    uint4 ra0 = *(const uint4*)(pA);
    uint4 ra1 = *(const uint4*)(pA + 8);
    uint4 rb0 = *(const uint4*)(pB0);
    uint4 rb1 = *(const uint4*)(pB1);
    uint4 rb2 = {0,0,0,0};
    if (b3) rb2 = *(const uint4*)(pB2);
    *(uint4*)(lds + aoff0) = ra0;
    *(uint4*)(lds + aoff1) = ra1;
    *(uint4*)(lds + boff0) = rb0;
    *(uint4*)(lds + boff1) = rb1;
    if (b3) *(uint4*)(lds + boff2) = rb2;
    __syncthreads();
    if (KC > 1){
        ra0 = *(const uint4*)(pA + 32);  ra1 = *(const uint4*)(pA + 40);
        rb0 = *(const uint4*)(pB0 + 32); rb1 = *(const uint4*)(pB1 + 32);
        if (b3) rb2 = *(const uint4*)(pB2 + 32);
    }

    for (int kc=0; kc<KC; ++kc){
        short* cbuf = lds + (kc & 1)*BUF;
        short* nbuf = lds + ((kc+1) & 1)*BUF;
        if (kc+1 < KC){
            *(uint4*)(nbuf + aoff0) = ra0;
            *(uint4*)(nbuf + aoff1) = ra1;
            *(uint4*)(nbuf + boff0) = rb0;
            *(uint4*)(nbuf + boff1) = rb1;
            if (b3) *(uint4*)(nbuf + boff2) = rb2;
            if (kc+2 < KC){
                const bf16* qA = pA + (kc+2)*32;
                ra0 = *(const uint4*)(qA); ra1 = *(const uint4*)(qA+8);
                rb0 = *(const uint4*)(pB0 + (kc+2)*32);
                rb1 = *(const uint4*)(pB1 + (kc+2)*32);
                if (b3) rb2 = *(const uint4*)(pB2 + (kc+2)*32);
            }
        }
        bf16x8 af[4], bfr[5];
        #pragma unroll
        for (int i=0;i<4;i++) af[i]  = *(const bf16x8*)(cbuf + ((wm*4+i)*64 + lane)*8);
        #pragma unroll
        for (int j=0;j<5;j++) bfr[j] = *(const bf16x8*)(cbuf + 4096 + ((wn*5+j)*64 + lane)*8);
        #pragma unroll
        for (int i=0;i<4;i++){
            #pragma unroll
            for (int j=0;j<5;j++)
                acc[i][j] = __builtin_amdgcn_mfma_f32_16x16x32_bf16(af[i], bfr[j], acc[i][j], 0, 0, 0);
        }
        __syncthreads();
    }

    int lq = lane >> 4, lr = lane & 15;
    #pragma unroll
    for (int i=0;i<4;i++){
        int rl = (wm*4+i)*16 + lq*4;
        #pragma unroll
        for (int j=0;j<5;j++){
            int cl = (wn*5+j)*16 + lr;
            float bv = bias[min(n0+cl, N-1)];
            #pragma unroll
            for (int r=0;r<4;r++){
                float v = acc[i][j][r] + bv;
                if (relu_out) v = fmaxf(v, 0.f);
                Ct[(rl+r)*CS + cl] = (short)__bfloat16_as_ushort(tob(v));
            }
        }
    }
    __syncthreads();
    // writeout: 128 rows x 20 col-chunks(8) = 2560 chunks, 10/thread
    #pragma unroll
    for (int p=0;p<10;p++){
        int c = p*256 + tid;
        int row = c / 20, colc = c - (c/20)*20;
        int grow = m0 + row, gcol = n0 + colc*8;
        if (grow < M && gcol < N){
            union { short s8[8]; uint4 v; } u;
            u.v = *(uint4*)&Ct[row*CS + colc*8];
            if (R){
                const bf16* rp = &R[(size_t)grow*ldc + gcol];
                #pragma unroll
                for (int e=0;e<8;e++){
                    float v = b2f((unsigned short)u.s8[e]) + tof(rp[e]);
                    u.s8[e] = (short)__bfloat16_as_ushort(tob(v));
                }
            }
            *(uint4*)&C[(size_t)grow*ldc + gcol] = u.v;
        }
    }
}

__global__ __launch_bounds__(256) void k_gemm160(const bf16* __restrict__ A, const bf16* __restrict__ Bt,
        const float* __restrict__ bias, const bf16* __restrict__ R, bf16* __restrict__ C,
        int M, int N, int Kp, int ldc, int relu_out){
    __shared__ __align__(16) char ldsbuf[43008];
    int nwg = gridDim.x*gridDim.y;
    int w = xcd_swz(blockIdx.y*gridDim.x + blockIdx.x, nwg);
    gemm160_body(A, Bt, bias, R, C, M, N, Kp, ldc, relu_out, (short*)ldsbuf,
                 (w/gridDim.x)*128, (w%gridDim.x)*160);
}

__global__ __launch_bounds__(256) void k_gemm160z(
        const bf16* __restrict__ A0, const bf16* __restrict__ A1,
        const bf16* __restrict__ Bt0, const bf16* __restrict__ Bt1,
        const float* __restrict__ bias0, const float* __restrict__ bias1,
        const bf16* __restrict__ R0, const bf16* __restrict__ R1,
        bf16* __restrict__ C0, bf16* __restrict__ C1,
        int M, int N, int Kp, int ldc, int relu0, int relu1){
    __shared__ __align__(16) char ldsbuf[43008];
    int nwg = gridDim.x*gridDim.y;
    int w = xcd_swz(blockIdx.y*gridDim.x + blockIdx.x, nwg);
    int m0 = (w/gridDim.x)*128, n0 = (w%gridDim.x)*160;
    if (blockIdx.z == 0) gemm160_body(A0, Bt0, bias0, R0, C0, M, N, Kp, ldc, relu0, (short*)ldsbuf, m0, n0);
    else                 gemm160_body(A1, Bt1, bias1, R1, C1, M, N, Kp, ldc, relu1, (short*)ldsbuf, m0, n0);
}

// enc-l2 g2 (BN160) + gate finisher in one dispatch: [0,470) gemm blocks, [470,588) gate blocks
__global__ __launch_bounds__(256) void k_g160gate(
        const bf16* __restrict__ A, const bf16* __restrict__ Bt, const float* __restrict__ bias,
        const bf16* __restrict__ R, bf16* __restrict__ C,
        const float* __restrict__ glogit, const float* __restrict__ bg2,
        const float* __restrict__ gumbel, float* __restrict__ gate){
    __shared__ __align__(16) char ldsbuf[43008];
    int bid = blockIdx.x;
    if (bid < 470){
        int w = xcd_swz(bid, 470);
        gemm160_body(A, Bt, bias, R, C, NN, EMB, SHID, SEM, 1, (short*)ldsbuf,
                     (w>>1)*128, (w&1)*160);
    } else {
        int i = (bid-470)*256 + threadIdx.x;
        if (i >= NN) return;
        float l0 = glogit[2*i]   + bg2[0] + gumbel[2*i];
        float l1 = glogit[2*i+1] + bg2[1] + gumbel[2*i+1];
        float m = fmaxf(l0, l1);
        float e0 = expf(l0-m), e1 = expf(l1-m);
        gate[i] = e1/(e0+e1);
    }
}

// ---------------- gate GEMM: logits from acc registers, no C write ----------------
// logit[row][t] = sum_col relu(acc+bias) * Wg2[col*2+t]; 16-lane shfl reduce + atomicAdd.
__device__ __forceinline__ void gate_gemm_body(const bf16* __restrict__ A, const bf16* __restrict__ Bt,
        const float* __restrict__ bias, const float* __restrict__ Wg2, float* __restrict__ glogit,
        int M, int N, int Kp, short* lds, int m0, int n0){
    int tid = threadIdx.x;
    int wave = tid >> 6, lane = tid & 63;
    int wm = wave >> 1, wn = wave & 1;

    int srow = tid >> 1;
    int sq   = (tid & 1) * 2;
    int grA = min(m0 + srow, M-1);
    int grB = min(n0 + srow, N-1);
    const bf16* pA = A  + (size_t)grA*Kp + sq*8;
    const bf16* pB = Bt + (size_t)grB*Kp + sq*8;
    int aoff0 = ((srow>>4)*64 +  sq   *16 + (srow&15))*8;
    int aoff1 = ((srow>>4)*64 + (sq+1)*16 + (srow&15))*8;

    f32x4 acc[4][4];
    #pragma unroll
    for (int i=0;i<4;i++){
        #pragma unroll
        for (int j=0;j<4;j++) acc[i][j] = (f32x4){0.f,0.f,0.f,0.f};
    }

    int KC = Kp >> 5;
    uint4 ra0 = *(const uint4*)(pA);
    uint4 ra1 = *(const uint4*)(pA + 8);
    uint4 rb0 = *(const uint4*)(pB);
    uint4 rb1 = *(const uint4*)(pB + 8);
    *(uint4*)(lds + aoff0)        = ra0;
    *(uint4*)(lds + aoff1)        = ra1;
    *(uint4*)(lds + 4096 + aoff0) = rb0;
    *(uint4*)(lds + 4096 + aoff1) = rb1;
    __syncthreads();
    if (KC > 1){
        ra0 = *(const uint4*)(pA + 32); ra1 = *(const uint4*)(pA + 40);
        rb0 = *(const uint4*)(pB + 32); rb1 = *(const uint4*)(pB + 40);
    }

    for (int kc=0; kc<KC; ++kc){
        short* cbuf = lds + (kc & 1)*8192;
        short* nbuf = lds + ((kc+1) & 1)*8192;
        if (kc+1 < KC){
            *(uint4*)(nbuf + aoff0)        = ra0;
            *(uint4*)(nbuf + aoff1)        = ra1;
            *(uint4*)(nbuf + 4096 + aoff0) = rb0;
            *(uint4*)(nbuf + 4096 + aoff1) = rb1;
            if (kc+2 < KC){
                const bf16* qA = pA + (kc+2)*32;
                const bf16* qB = pB + (kc+2)*32;
                ra0 = *(const uint4*)(qA); ra1 = *(const uint4*)(qA+8);
                rb0 = *(const uint4*)(qB); rb1 = *(const uint4*)(qB+8);
            }
        }
        bf16x8 af[4], bfr[4];
        #pragma unroll
        for (int i=0;i<4;i++) af[i]  = *(const bf16x8*)(cbuf + ((wm*4+i)*64 + lane)*8);
        #pragma unroll
        for (int j=0;j<4;j++) bfr[j] = *(const bf16x8*)(cbuf + 4096 + ((wn*4+j)*64 + lane)*8);
        #pragma unroll
        for (int i=0;i<4;i++){
            #pragma unroll
            for (int j=0;j<4;j++)
                acc[i][j] = __builtin_amdgcn_mfma_f32_16x16x32_bf16(af[i], bfr[j], acc[i][j], 0, 0, 0);
        }
        __syncthreads();
    }

    int lq = lane >> 4, lr = lane & 15;
    #pragma unroll
    for (int i=0;i<4;i++){
        #pragma unroll
        for (int r=0;r<4;r++){
            int row = m0 + (wm*4+i)*16 + lq*4 + r;
            float p0 = 0.f, p1 = 0.f;
            #pragma unroll
            for (int j=0;j<4;j++){
                int cl = (wn*4+j)*16 + lr;
                int col = n0 + cl;
                float v = fmaxf(acc[i][j][r] + bias[min(col, N-1)], 0.f);
                if (col < N){ p0 += v * Wg2[col*2]; p1 += v * Wg2[col*2+1]; }
            }
            #pragma unroll
            for (int m=1; m<16; m<<=1){ p0 += __shfl_xor(p0, m); p1 += __shfl_xor(p1, m); }
            if (lr == 0 && row < M){
                atomicAdd(&glogit[row*2],   p0);
                atomicAdd(&glogit[row*2+1], p1);
            }
        }
    }
}

// hetero pair: [0,1175) gate-gemm (cur_r @ Wg1 -> logits), [1175,2350) enc-l2 g1 (normal)
__global__ __launch_bounds__(256) void k_gatepair(
        const bf16* __restrict__ Ag, const bf16* __restrict__ Btg, const float* __restrict__ bg,
        const float* __restrict__ Wg2, float* __restrict__ glogit,
        const bf16* __restrict__ A1, const bf16* __restrict__ Bt1, const float* __restrict__ b1,
        bf16* __restrict__ C1){
    __shared__ __align__(16) char ldsbuf[34816];
    int bid = blockIdx.x;
    if (bid < 1175){
        int w = xcd_swz(bid, 1175);
        gate_gemm_body(Ag, Btg, bg, Wg2, glogit, NN, HID, SEM, (short*)ldsbuf,
                       (w/5)*128, (w%5)*128);
    } else {
        int w = xcd_swz(bid - 1175, 1175);
        gemm_body(A1, Bt1, b1, nullptr, C1, NN, HID, SEM, SHID, 1, (short*)ldsbuf,
                  (w/5)*128, (w%5)*128);
    }
}

// ---------------- sim machinery (device) ----------------
__device__ __forceinline__ void stage_tile(const short* __restrict__ P, int RB, int K, int r0, int k0,
                                           short (*lds)[64][8], int tid){
    #pragma unroll
    for (int s=0;s<2;s++){
        int seg = tid*2+s;
        int row = seg>>2, q = seg&3;
        int gr = r0 + row;
        int gk = k0 + q*8;
        union { short s8[8]; uint4 v; } u;
        if (gr < RB && gk + 8 <= K){
            const uint2* p = (const uint2*)(P + (size_t)gr*K + gk);
            uint2 lo = p[0], hi = p[1];
            u.v.x = lo.x; u.v.y = lo.y; u.v.z = hi.x; u.v.w = hi.y;
        } else {
            #pragma unroll
            for (int j=0;j<8;j++){
                int kk = gk + j;
                u.s8[j] = (gr < RB && kk < K) ? P[(size_t)gr*K + kk] : (short)0;
            }
        }
        *(uint4*)&lds[row>>4][q*16 + (row&15)][0] = u.v;
    }
}

// sim_cp rowsums: S[i] += sum_j exp((hr_i.henv_j)*5/(na_i*nc_j+1e-8)); matrix never materialized
__device__ __forceinline__ void sim_body(const bf16* __restrict__ A, const bf16* __restrict__ Bt,
                      const float* __restrict__ na, const float* __restrict__ nc, float* __restrict__ S,
                      char* ldsraw){
    short (*Asl)[64][8] = (short(*)[64][8])ldsraw;
    short (*Bsl)[64][8] = (short(*)[64][8])(ldsraw + 8192);
    int tid = threadIdx.x;
    int wave = tid >> 6, lane = tid & 63;
    int wm = wave >> 1, wn = wave & 1;
    int m0 = blockIdx.y*128, n0 = blockIdx.x*128;
    f32x4 acc[4][4];
    #pragma unroll
    for (int i=0;i<4;i++){
        #pragma unroll
        for (int j=0;j<4;j++) acc[i][j] = (f32x4){0.f,0.f,0.f,0.f};
    }
    for (int k0=0; k0<SEM; k0+=32){
        stage_tile((const short*)A,  NG, SEM, m0, k0, Asl, tid);
        stage_tile((const short*)Bt, NG, SEM, n0, k0, Bsl, tid);
        __syncthreads();
        bf16x8 af[4], bfr[4];
        #pragma unroll
        for (int i=0;i<4;i++) af[i]  = *(const bf16x8*)&Asl[wm*4+i][lane][0];
        #pragma unroll
        for (int j=0;j<4;j++) bfr[j] = *(const bf16x8*)&Bsl[wn*4+j][lane][0];
        #pragma unroll
        for (int i=0;i<4;i++){
            #pragma unroll
            for (int j=0;j<4;j++)
                acc[i][j] = __builtin_amdgcn_mfma_f32_16x16x32_bf16(af[i], bfr[j], acc[i][j], 0, 0, 0);
        }
        __syncthreads();
    }
    int lq = lane >> 4, lr = lane & 15;
    #pragma unroll
    for (int i=0;i<4;i++){
        #pragma unroll
        for (int r=0;r<4;r++){
            int row = m0 + (wm*4+i)*16 + lq*4 + r;
            float nar = na[min(row, NG-1)];
            float rsum = 0.f;
            #pragma unroll
            for (int j=0;j<4;j++){
                int col = n0 + (wn*4+j)*16 + lr;
                float ncj = nc[min(col, NG-1)];
                float e = expf(acc[i][j][r] * 5.0f / (nar*ncj + 1e-8f));
                if (row < NG && col < NG) rsum += e;
            }
            #pragma unroll
            for (int m=1; m<16; m<<=1) rsum += __shfl_xor(rsum, m);
            if (lr == 0 && row < NG) atomicAdd(&S[row], rsum);
        }
    }
}

// fat kernel: z=0 -> sim rowsums (grid 12x12), z=1 -> head GEMM (grid 5x24)
__global__ __launch_bounds__(256) void k_simhead(const bf16* __restrict__ hrb, const bf16* __restrict__ henvb,
        const float* __restrict__ na, const float* __restrict__ nc, float* __restrict__ Ssum,
        const bf16* __restrict__ Pbuf, const bf16* __restrict__ wtp1, const float* __restrict__ bp1,
        bf16* __restrict__ hidP){
    __shared__ __align__(16) char ldsbuf[34816];
    if (blockIdx.z == 0){
        if (blockIdx.x >= 12 || blockIdx.y >= 12) return;
        sim_body(hrb, henvb, na, nc, Ssum, ldsbuf);
    } else {
        if (blockIdx.x >= 5) return;
        gemm_body(Pbuf, wtp1, bp1, nullptr, hidP, 2*NG, HID, SEM, SHID, 1, (short*)ldsbuf,
                  blockIdx.y*128, blockIdx.x*128);
    }
}

// ---------------- fused pooling + mean + norms + P top half (one block per graph) ----------------
// sums stay in registers: kills the sumh/sumgh round-trip and the k_meannorm dispatch
__global__ __launch_bounds__(320) void k_poolmean(const bf16* __restrict__ h, const float* __restrict__ gate,
                      const int* __restrict__ gstart, float* __restrict__ hr, float* __restrict__ henv,
                      bf16* __restrict__ hrb, bf16* __restrict__ henvb, bf16* __restrict__ P,
                      float* __restrict__ na, float* __restrict__ nc, float* __restrict__ pos,
                      float* __restrict__ rnum, float* __restrict__ cntf, float* __restrict__ Ssum){
    int g = blockIdx.x, c = threadIdx.x;
    int n0 = gstart[g], n1 = gstart[g+1];
    float sh=0.f, sg=0.f, sgate=0.f;
    if (c < EMB){
        for (int n=n0;n<n1;n++){
            float v = tof(h[(size_t)n*SEM+c]);
            float gt = gate[n];
            sh += v; sg += gt*v;
            if (c==0) sgate += gt;
        }
    }
    float cnt = (float)(n1-n0);
    float inv = 1.f / fmaxf(cnt, 1.f);
    float r=0.f, e=0.f, o=0.f;
    int idx = g*SEM + c;
    if (c < EMB){
        int off = g*EMB + c;
        r = sg*inv; e = (sh-sg)*inv; o = sh*inv;
        hr[off] = r; henv[off] = e;
        hrb[idx] = tob(r); henvb[idx] = tob(e); P[idx] = tob(r);
        if (c==0){ rnum[g] = sgate; cntf[g] = cnt; }
    } else {
        hrb[idx] = tob(0.f); henvb[idx] = tob(0.f); P[idx] = tob(0.f);   // zero pads (B-operands!)
        if (c == 319) Ssum[g] = 0.f;
    }
    float srr=r*r, soo=o*o, see=e*e, sro=r*o;
    #pragma unroll
    for (int off=32; off>0; off>>=1){
        srr += __shfl_down(srr,off); soo += __shfl_down(soo,off);
        see += __shfl_down(see,off); sro += __shfl_down(sro,off);
    }
    __shared__ float ws[4][5];
    int wv = c >> 6, ln = c & 63;
    if (ln == 0){ ws[0][wv]=srr; ws[1][wv]=soo; ws[2][wv]=see; ws[3][wv]=sro; }
    __syncthreads();
    if (c == 0){
        float a=0.f,b=0.f,c2=0.f,d=0.f;
        #pragma unroll
        for (int i=0;i<5;i++){ a+=ws[0][i]; b+=ws[1][i]; c2+=ws[2][i]; d+=ws[3][i]; }
        float sa = sqrtf(a), sb = sqrtf(b), sc = sqrtf(c2);
        na[g] = sa; nc[g] = sc;
        pos[g] = expf(d/(sa*sb + 1e-8f) * 5.0f);
    }
}

// P bottom half: needs OTHER graphs' henv (perm) -> separate dispatch after k_poolmean
__global__ __launch_bounds__(256) void k_pbuild2(const float* __restrict__ hr, const float* __restrict__ henv,
                      const int* __restrict__ perm, bf16* __restrict__ P){
    int idx = blockIdx.x*256 + threadIdx.x;
    if (idx >= NG*SEM) return;
    int g = idx / SEM, c = idx - g*SEM;
    P[(size_t)(NG+g)*SEM + c] = (c < EMB)
        ? tob(hr[g*EMB+c] + henv[(size_t)perm[g]*EMB + c])
        : tob(0.f);
}

// pred (blocks 0..749) + loss (block 750) fused: all loss inputs ready before this dispatch
__global__ __launch_bounds__(256) void k_predloss(const bf16* __restrict__ hidP, const float* __restrict__ Wp2,
                      const float* __restrict__ bp2, const float* __restrict__ cntf,
                      const float* __restrict__ rnum, const float* __restrict__ pos,
                      const float* __restrict__ S, float* __restrict__ out){
    if (blockIdx.x == 750){
        __shared__ float ra[256], rb[256];
        int t = threadIdx.x;
        float a=0.f, b=0.f;
        for (int g=t; g<NG; g+=256){
            float r = rnum[g] + 1e-8f;
            float e = (cntf[g] - rnum[g]) + 1e-8f;
            a += fabsf(r/(r+e) - 0.4f);
            float p = pos[g];
            b += -logf(p/(S[g]+p));
        }
        ra[t]=a; rb[t]=b; __syncthreads();
        for (int off=128; off>0; off>>=1){ if (t<off){ ra[t]+=ra[t+off]; rb[t]+=rb[t+off]; } __syncthreads(); }
        if (t==0){
            out[2*NG*NTASK]   = ra[0]/NG;
            out[2*NG*NTASK+1] = rb[0]/NG;
        }
        return;
    }
    int r = blockIdx.x*4 + (threadIdx.x >> 6);
    int lane = threadIdx.x & 63;
    if (r >= 2*NG) return;
    float acc[NTASK];
    #pragma unroll
    for (int t=0;t<NTASK;t++) acc[t] = 0.f;
    for (int i=lane;i<HID;i+=64){
        float h = tof(hidP[(size_t)r*SHID+i]);
        const float4* wp = (const float4*)&Wp2[i*NTASK];
        float4 wa = wp[0], wb = wp[1], wc = wp[2];
        acc[0]+=h*wa.x; acc[1]+=h*wa.y; acc[2]+=h*wa.z; acc[3]+=h*wa.w;
        acc[4]+=h*wb.x; acc[5]+=h*wb.y; acc[6]+=h*wb.z; acc[7]+=h*wb.w;
        acc[8]+=h*wc.x; acc[9]+=h*wc.y; acc[10]+=h*wc.z; acc[11]+=h*wc.w;
    }
    #pragma unroll
    for (int t=0;t<NTASK;t++){
        for (int off=32; off>0; off>>=1) acc[t] += __shfl_down(acc[t], off);
    }
    if (lane==0){
        float* dst = (r < NG) ? &out[NG*NTASK + r*NTASK] : &out[(r-NG)*NTASK];
        #pragma unroll
        for (int t=0;t<NTASK;t++) dst[t] = acc[t] + bp2[t];
    }
}

extern "C" void kernel_launch(void* const* d_in, const int* in_sizes, int n_in,
                              void* d_out, int out_size, void* d_ws, size_t ws_size,
                              hipStream_t stream) {
    const float* x      = (const float*)d_in[0];
    const float* eattr  = (const float*)d_in[1];
    const int*   eidx   = (const int*)d_in[2];
    const int*   batch  = (const int*)d_in[3];
    const float* gumbel = (const float*)d_in[4];
    const int*   perm   = (const int*)d_in[5];
    const float* W_enc  = (const float*)d_in[6];
    const float* b_enc  = (const float*)d_in[7];
    const float* We_g   = (const float*)d_in[8];
    const float* be_g   = (const float*)d_in[9];
    const float* W1_g   = (const float*)d_in[10];
    const float* b1_g   = (const float*)d_in[11];
    const float* W2_g   = (const float*)d_in[12];
    const float* b2_g   = (const float*)d_in[13];
    const float* We_r   = (const float*)d_in[14];
    const float* be_r   = (const float*)d_in[15];
    const float* W1_r   = (const float*)d_in[16];
    const float* b1_r   = (const float*)d_in[17];
    const float* W2_r   = (const float*)d_in[18];
    const float* b2_r   = (const float*)d_in[19];
    const float* Wg1    = (const float*)d_in[20];
    const float* bg1    = (const float*)d_in[21];
    const float* Wg2    = (const float*)d_in[22];
    const float* bg2    = (const float*)d_in[23];
    const float* Wp1    = (const float*)d_in[24];
    const float* bp1    = (const float*)d_in[25];
    const float* Wp2    = (const float*)d_in[26];
    const float* bp2    = (const float*)d_in[27];
    float* out = (float*)d_out;

    const int* srcArr = eidx;
    const int* dstArr = eidx + NE;

    // ---- workspace (bump allocator, 256B aligned) ----
    char* w = (char*)d_ws;
    size_t off = 0;
    auto alloc = [&](size_t bytes)->char*{ char* p = w + off; off += (bytes + 255) & ~(size_t)255; return p; };
    bf16* xfeat = (bf16*)alloc((size_t)NN*SEM*2);
    bf16* cur_r = (bf16*)alloc((size_t)NN*SEM*2);
    bf16* cur_g = (bf16*)alloc((size_t)NN*SEM*2);
    bf16* apx   = (bf16*)alloc((size_t)NN*SEM*2);     // rationale-side agg out
    bf16* apx2  = (bf16*)alloc((size_t)NN*SEM*2);     // encoder-side agg out
    char* midc  = alloc((size_t)NN*SHID*2);           // mid_r; reused after trunk:
    bf16* mid_r = (bf16*)midc;
    bf16* Pbuf   = (bf16*)(midc + 12*1024*1024);
    bf16* hidP   = (bf16*)(midc + 20*1024*1024);
    bf16* mid_g = (bf16*)alloc((size_t)NN*SHID*2);
    bf16* wt1g  = (bf16*)alloc((size_t)5*HID*SEM*2);
    bf16* wt2g  = (bf16*)alloc((size_t)5*EMB*SHID*2);
    bf16* wt1r  = (bf16*)alloc((size_t)2*HID*SEM*2);
    bf16* wt2r  = (bf16*)alloc((size_t)2*EMB*SHID*2);
    bf16* wtg1  = (bf16*)alloc((size_t)HID*SEM*2);
    bf16* wtp1  = (bf16*)alloc((size_t)HID*SEM*2);
    float4* epack = (float4*)alloc((size_t)NE*16);
    float* gate  = (float*)alloc((size_t)NN*4);
    float* glogit= (float*)alloc((size_t)NN*2*4);
    float* hr    = (float*)alloc((size_t)NG*EMB*4);
    float* henv  = (float*)alloc((size_t)NG*EMB*4);
    bf16* hrb    = (bf16*)alloc((size_t)NG*SEM*2);
    bf16* henvb  = (bf16*)alloc((size_t)NG*SEM*2);
    float* rnum  = (float*)alloc(NG*4);
    float* cntf  = (float*)alloc(NG*4);
    float* na    = (float*)alloc(NG*4);
    float* ncv   = (float*)alloc(NG*4);
    float* pos   = (float*)alloc(NG*4);
    float* Ssum  = (float*)alloc(NG*4);
    int* deg     = (int*)alloc((size_t)NN*4);
    int* indptr  = (int*)alloc((size_t)(NN+1)*4);
    int* cursor  = (int*)alloc((size_t)NN*4);
    int* gstart  = (int*)alloc((size_t)(NG+1)*4);
    int* bsum    = (int*)alloc((size_t)NBLK_SCAN*4);
    int* boff    = (int*)alloc((size_t)NBLK_SCAN*4);

    const int NB_NE  = (NE+255)/256;
    const int NB_AG  = (NN*CG+255)/256;
    const int NB_GP  = (NG*SEM+255)/256;

    // ---- batched preamble: transposes + zeros + gstart + encoder, ONE dispatch ----
    dim3 gwp(19, 19, 18 + 98);
    k_wprep_all<<<gwp, 256, 0, stream>>>(W1_g, W2_g, W1_r, W2_r, Wg1, Wp1,
                                         wt1g, wt2g, wt1r, wt2r, wtg1, wtp1,
                                         deg, batch, gstart, x, W_enc, b_enc, xfeat, glogit);

    // ---- CSR build + fused scatter/edge-pack ----
    k_hist       <<<NB_NE, 256, 0, stream>>>(dstArr, deg);
    k_scanA      <<<NBLK_SCAN, 256, 0, stream>>>(deg, bsum);
    k_scanB      <<<1, 128, 0, stream>>>(bsum, boff);
    k_scanC      <<<NBLK_SCAN, 256, 0, stream>>>(deg, boff, indptr, cursor);
    k_scatterprep<<<NB_NE, 256, 0, stream>>>(dstArr, srcArr, eattr, cursor, epack);

    dim3 gm1z((HID+127)/128, (NN+127)/128, 2);   // N=600 pairs: (5,235,2)
    dim3 gm160z(2, (NN+127)/128, 2);             // N=300 BN160 pairs: (2,235,2)
    dim3 gm1((HID+127)/128, (NN+127)/128);       // solo N600
    dim3 gm160(2, (NN+127)/128);                 // solo N300 BN160

    // ---- layer 0 (both stacks): shared-gather dual agg, then paired GEMMs ----
    k_agg4d<<<NB_AG, 256, 0, stream>>>(xfeat, We_r, be_r, We_g, be_g, epack, indptr, apx, apx2);
    k_gemm2z<<<gm1z, 256, 0, stream>>>(apx, apx2, wt1r, wt1g, b1_r, b1_g,
                                       nullptr, nullptr, mid_r, mid_g, NN, HID, SEM, SHID, 1, 1);
    k_gemm160z<<<gm160z, 256, 0, stream>>>(mid_r, mid_g, wt2r, wt2g, b2_r, b2_g,
                                           xfeat, xfeat, cur_r, cur_g, NN, EMB, SHID, SEM, 1, 1);

    // ---- layer 1 (both stacks): dual-SOURCE agg (one epack pass) + paired GEMMs ----
    k_agg4dd<<<NB_AG, 256, 0, stream>>>(cur_r, cur_g, We_r + 3*EMB, be_r + EMB,
                                        We_g + 3*EMB, be_g + EMB, epack, indptr, apx, apx2);
    k_gemm2z<<<gm1z, 256, 0, stream>>>(apx, apx2, wt1r + (size_t)HID*SEM, wt1g + (size_t)HID*SEM,
                                       b1_r + HID, b1_g + HID, nullptr, nullptr, mid_r, mid_g,
                                       NN, HID, SEM, SHID, 1, 1);
    k_gemm160z<<<gm160z, 256, 0, stream>>>(mid_r, mid_g, wt2r + (size_t)EMB*SHID, wt2g + (size_t)EMB*SHID,
                                           b2_r + EMB, b2_g + EMB, cur_r, cur_g, cur_r, cur_g,
                                           NN, EMB, SHID, SEM, 0, 1);   // rationale last layer: no relu

    // ---- encoder layer 2 agg; (gate-gemm -> logits) paired with enc-l2 g1; g2+gatefin fused ----
    k_agg4 <<<NB_AG, 256, 0, stream>>>(cur_g, We_g + 2*3*EMB, be_g + 2*EMB, epack, indptr, apx2);
    k_gatepair<<<2350, 256, 0, stream>>>(cur_r, wtg1, bg1, Wg2, glogit,
                                         apx2, wt1g + (size_t)2*HID*SEM, b1_g + 2*HID, mid_g);
    k_g160gate<<<588, 256, 0, stream>>>(mid_g, wt2g + (size_t)2*EMB*SHID, b2_g + 2*EMB, cur_g, cur_g,
                                        glogit, bg2, gumbel, gate);

    // ---- encoder layers 3,4 (solo, swizzled; round-8 row-split pipeline regressed -> reverted) ----
    for (int l=3; l<5; l++){
        k_agg4 <<<NB_AG, 256, 0, stream>>>(cur_g, We_g + l*3*EMB, be_g + l*EMB, epack, indptr, apx2);
        k_gemm2<<<gm1, 256, 0, stream>>>(apx2, wt1g + (size_t)l*HID*SEM, b1_g + l*HID, nullptr, mid_g,
                                         NN, HID, SEM, SHID, 1);
        k_gemm160<<<gm160, 256, 0, stream>>>(mid_g, wt2g + (size_t)l*EMB*SHID, b2_g + l*EMB, cur_g, cur_g,
                                             NN, EMB, SHID, SEM, (l<4)?1:0);
    }
    // cur_g now holds h_node (bf16, stride SEM)

    // ---- fused pooling + mean + norms ----
    k_poolmean<<<NG, 320, 0, stream>>>(cur_g, gate, gstart, hr, henv, hrb, henvb, Pbuf,
                                       na, ncv, pos, rnum, cntf, Ssum);
    k_pbuild2 <<<NB_GP, 256, 0, stream>>>(hr, henv, perm, Pbuf);
    // ---- contrastive sim rowsums + head GEMM in one fat dispatch ----
    dim3 gsh(12, 24, 2);
    k_simhead<<<gsh, 256, 0, stream>>>(hrb, henvb, na, ncv, Ssum, Pbuf, wtp1, bp1, hidP);
    // ---- pred + loss fused ----
    k_predloss<<<751, 256, 0, stream>>>(hidP, Wp2, bp2, cntf, rnum, pos, Ssum, out);
}

// Round 10
// 845.242 us; speedup vs baseline: 1.0425x; 1.0037x over previous
//
#include <hip/hip_runtime.h>
#include <hip/hip_bf16.h>

typedef __hip_bfloat16 bf16;
typedef __attribute__((ext_vector_type(8))) short bf16x8;
typedef __attribute__((ext_vector_type(4))) float f32x4;

#define NN 30000      // nodes
#define NE 240000     // edges
#define NG 1500       // graphs
#define EMB 300
#define HID 600
#define NTASK 12
#define SEM 320       // padded stride for EMB-dim tensors
#define SHID 608      // padded stride for HID-dim tensors
#define CG 75         // 4-channel groups — 75 thr/node: best TLP (round-9 lesson)
#define NBLK_SCAN 118 // (NN+255)/256

__device__ __forceinline__ float tof(bf16 v){ return __bfloat162float(v); }
__device__ __forceinline__ bf16  tob(float v){ return __float2bfloat16(v); }
__device__ __forceinline__ float b2f(unsigned short u){ return __uint_as_float(((unsigned)u)<<16); }

// bijective XCD-aware block swizzle (m204): dispatch slot orig lands on XCD orig%8 (RR);
// give each XCD a CONTIGUOUS tile range so column-tiles sharing an A row-panel hit one L2.
__device__ __forceinline__ int xcd_swz(int orig, int nwg){
    int q = nwg >> 3, r = nwg & 7;
    int x = orig & 7, w = orig >> 3;
    return (x < r ? x*(q+1) : r*(q+1) + (x-r)*q) + w;
}

// ---------------- CSR build (by dst) ----------------
__global__ __launch_bounds__(256) void k_scanA(const int* __restrict__ deg, int* __restrict__ bsum){
    __shared__ int red[256];
    int b = blockIdx.x, t = threadIdx.x;
    int i = b*256 + t;
    red[t] = (i < NN) ? deg[i] : 0;
    __syncthreads();
    for (int off=128; off>0; off>>=1){ if (t<off) red[t]+=red[t+off]; __syncthreads(); }
    if (t==0) bsum[b] = red[0];
}

__global__ __launch_bounds__(128) void k_scanB(const int* __restrict__ bsum, int* __restrict__ boff){
    __shared__ int s[128];
    int t = threadIdx.x;
    int v = (t < NBLK_SCAN) ? bsum[t] : 0;
    s[t] = v;
    __syncthreads();
    for (int off=1; off<128; off<<=1){
        int add = (t>=off) ? s[t-off] : 0;
        __syncthreads();
        s[t] += add;
        __syncthreads();
    }
    if (t < NBLK_SCAN) boff[t] = s[t] - v;   // exclusive
}

__global__ __launch_bounds__(256) void k_scanC(const int* __restrict__ deg, const int* __restrict__ boff,
                                               int* __restrict__ indptr, int* __restrict__ cursor){
    __shared__ int s[256];
    int b = blockIdx.x, t = threadIdx.x;
    int i = b*256 + t;
    int v = (i < NN) ? deg[i] : 0;
    s[t] = v;
    __syncthreads();
    for (int off=1; off<256; off<<=1){
        int add = (t>=off) ? s[t-off] : 0;
        __syncthreads();
        s[t] += add;
        __syncthreads();
    }
    int excl = s[t] - v + boff[b];
    if (i < NN){ indptr[i] = excl; cursor[i] = excl; }
    if (i == 0) indptr[NN] = NE;
}

// scatter + edge pack fused: write epack directly at the atomic cursor slot (no eid pass)
__global__ __launch_bounds__(256) void k_scatterprep(const int* __restrict__ dst, const int* __restrict__ src,
                      const float* __restrict__ eattr, int* __restrict__ cursor, float4* __restrict__ epack){
    int e = blockIdx.x*256 + threadIdx.x;
    if (e >= NE) return;
    int p = atomicAdd(&cursor[dst[e]], 1);
    float4 q;
    q.x = __int_as_float(src[e]);
    q.y = eattr[e*3]; q.z = eattr[e*3+1]; q.w = eattr[e*3+2];
    epack[p] = q;
}

// ---------------- batched preamble: weight transposes + gstart + node encoder + edge histogram ----
// z: 0..4 W1_g | 5..9 W2_g | 10..11 W1_r | 12..13 W2_r | 14 Wg1 | 15 Wp1 | 16 hist slice 0
//    | 17 gstart | 18..115 node-encoder slices | 116..117 hist slices 1..2
// deg/glogit pre-zeroed via hipMemsetAsync (stream-ordered before this dispatch)
__global__ __launch_bounds__(256) void k_wprep_all(
        const float* __restrict__ W1_g, const float* __restrict__ W2_g,
        const float* __restrict__ W1_r, const float* __restrict__ W2_r,
        const float* __restrict__ Wg1,  const float* __restrict__ Wp1,
        bf16* __restrict__ wt1g, bf16* __restrict__ wt2g,
        bf16* __restrict__ wt1r, bf16* __restrict__ wt2r,
        bf16* __restrict__ wtg1, bf16* __restrict__ wtp1,
        int* __restrict__ deg, const int* __restrict__ batch, int* __restrict__ gstart,
        const float* __restrict__ x, const float* __restrict__ W_enc,
        const float* __restrict__ b_enc, bf16* __restrict__ xfeat,
        const int* __restrict__ dstArr){
    __shared__ float t[32][33];
    int z = blockIdx.z;
    if (z == 16 || z >= 116){
        int slice = (z == 16) ? 0 : (z - 115);   // 0,1,2
        int e = (slice*361 + blockIdx.y*19 + blockIdx.x)*256 + threadIdx.x;
        if (e < NE) atomicAdd(&deg[dstArr[e]], 1);
        return;
    }
    if (z >= 18){
        int idx = ((z-18)*361 + blockIdx.y*19 + blockIdx.x)*256 + threadIdx.x;
        if (idx >= NN*EMB) return;
        int n = idx / EMB, c = idx - n*EMB;
        float acc = b_enc[c];
        #pragma unroll
        for (int k=0;k<9;k++) acc += x[n*9+k] * W_enc[k*EMB+c];
        xfeat[(size_t)n*SEM + c] = tob(acc);
        return;
    }
    if (z == 17){
        int g = (blockIdx.y*19 + blockIdx.x)*256 + threadIdx.x;
        if (g > NG) return;
        if (g == NG){ gstart[NG] = NN; return; }
        int lo=0, hi=NN;
        while (lo<hi){ int mid=(lo+hi)>>1; if (batch[mid] < g) lo=mid+1; else hi=mid; }
        gstart[g] = lo;
        return;
    }
    const float* Ws; bf16* Wd; int K, Kp, N;
    if (z < 5)      { Ws = W1_g + (size_t)z*EMB*HID;      Wd = wt1g + (size_t)z*HID*SEM;      K=EMB; Kp=SEM;  N=HID; }
    else if (z < 10){ int l=z-5;  Ws = W2_g + (size_t)l*HID*EMB; Wd = wt2g + (size_t)l*EMB*SHID; K=HID; Kp=SHID; N=EMB; }
    else if (z < 12){ int l=z-10; Ws = W1_r + (size_t)l*EMB*HID; Wd = wt1r + (size_t)l*HID*SEM;  K=EMB; Kp=SEM;  N=HID; }
    else if (z < 14){ int l=z-12; Ws = W2_r + (size_t)l*HID*EMB; Wd = wt2r + (size_t)l*EMB*SHID; K=HID; Kp=SHID; N=EMB; }
    else if (z ==14){ Ws = Wg1; Wd = wtg1; K=EMB; Kp=SEM; N=HID; }
    else            { Ws = Wp1; Wd = wtp1; K=EMB; Kp=SEM; N=HID; }
    int n0 = blockIdx.x*32, k0 = blockIdx.y*32;
    if (n0 >= N || k0 >= Kp) return;
    int tx = threadIdx.x & 31, ty = threadIdx.x >> 5;
    #pragma unroll
    for (int i=0;i<4;i++){
        int k = k0 + ty + i*8, n = n0 + tx;
        t[ty+i*8][tx] = (k<K && n<N) ? Ws[(size_t)k*N+n] : 0.f;
    }
    __syncthreads();
    #pragma unroll
    for (int i=0;i<4;i++){
        int n = n0 + ty + i*8, k = k0 + tx;
        if (n<N && k<Kp) Wd[(size_t)n*Kp+k] = tob(t[tx][ty+i*8]);
    }
}

// ---------------- agg body (device): thread=(node, 4-ch group), 2-deep pipeline ----------------
__device__ __forceinline__ void agg4_body(const bf16* __restrict__ cur, const float* __restrict__ We,
                      const float* __restrict__ be, const float4* __restrict__ epack,
                      const int* __restrict__ indptr, bf16* __restrict__ apx, int idx){
    int n = idx / CG, cg = idx - n*CG;
    int c0 = cg*4;
    float w0[4], w1[4], w2[4], bbv[4], acc[4];
    #pragma unroll
    for (int j=0;j<4;j++){
        w0[j] = We[c0+j]; w1[j] = We[EMB+c0+j]; w2[j] = We[2*EMB+c0+j]; bbv[j] = be[c0+j];
    }
    ushort4 hs = *(const ushort4*)&cur[(size_t)n*SEM + c0];
    acc[0]=b2f(hs.x); acc[1]=b2f(hs.y); acc[2]=b2f(hs.z); acc[3]=b2f(hs.w);
    int k  = indptr[n], k1 = indptr[n+1];

    auto accum4 = [&](float4 e0, float4 e1, float4 e2, float4 e3,
                      ushort4 ha, ushort4 hb, ushort4 hc, ushort4 hd){
        float fa[4] = {b2f(ha.x), b2f(ha.y), b2f(ha.z), b2f(ha.w)};
        float fb[4] = {b2f(hb.x), b2f(hb.y), b2f(hb.z), b2f(hb.w)};
        float fc[4] = {b2f(hc.x), b2f(hc.y), b2f(hc.z), b2f(hc.w)};
        float fd[4] = {b2f(hd.x), b2f(hd.y), b2f(hd.z), b2f(hd.w)};
        #pragma unroll
        for (int j=0;j<4;j++){
            float va = fa[j] + e0.y*w0[j] + e0.z*w1[j] + e0.w*w2[j] + bbv[j];
            float vb = fb[j] + e1.y*w0[j] + e1.z*w1[j] + e1.w*w2[j] + bbv[j];
            float vc = fc[j] + e2.y*w0[j] + e2.z*w1[j] + e2.w*w2[j] + bbv[j];
            float vd = fd[j] + e3.y*w0[j] + e3.z*w1[j] + e3.w*w2[j] + bbv[j];
            acc[j] += fmaxf(va, 0.f) + fmaxf(vb, 0.f) + fmaxf(vc, 0.f) + fmaxf(vd, 0.f);
        }
    };

    if (k + 4 <= k1){
        float4 e0 = epack[k], e1 = epack[k+1], e2 = epack[k+2], e3 = epack[k+3];
        ushort4 h0 = *(const ushort4*)&cur[(size_t)__float_as_int(e0.x)*SEM + c0];
        ushort4 h1 = *(const ushort4*)&cur[(size_t)__float_as_int(e1.x)*SEM + c0];
        ushort4 h2 = *(const ushort4*)&cur[(size_t)__float_as_int(e2.x)*SEM + c0];
        ushort4 h3 = *(const ushort4*)&cur[(size_t)__float_as_int(e3.x)*SEM + c0];
        while (k + 8 <= k1){
            float4 f0 = epack[k+4], f1 = epack[k+5], f2 = epack[k+6], f3 = epack[k+7];
            ushort4 g0 = *(const ushort4*)&cur[(size_t)__float_as_int(f0.x)*SEM + c0];
            ushort4 g1 = *(const ushort4*)&cur[(size_t)__float_as_int(f1.x)*SEM + c0];
            ushort4 g2 = *(const ushort4*)&cur[(size_t)__float_as_int(f2.x)*SEM + c0];
            ushort4 g3 = *(const ushort4*)&cur[(size_t)__float_as_int(f3.x)*SEM + c0];
            accum4(e0,e1,e2,e3, h0,h1,h2,h3);
            e0=f0; e1=f1; e2=f2; e3=f3;
            h0=g0; h1=g1; h2=g2; h3=g3;
            k += 4;
        }
        accum4(e0,e1,e2,e3, h0,h1,h2,h3);
        k += 4;
    }
    for (; k < k1; k++){
        float4 e0 = epack[k];
        int s0 = __float_as_int(e0.x);
        ushort4 ha = *(const ushort4*)&cur[(size_t)s0*SEM + c0];
        float fa[4] = {b2f(ha.x), b2f(ha.y), b2f(ha.z), b2f(ha.w)};
        #pragma unroll
        for (int j=0;j<4;j++){
            float va = fa[j] + e0.y*w0[j] + e0.z*w1[j] + e0.w*w2[j] + bbv[j];
            acc[j] += fmaxf(va, 0.f);
        }
    }
    ushort4 o;
    o.x = __bfloat16_as_ushort(tob(acc[0]));
    o.y = __bfloat16_as_ushort(tob(acc[1]));
    o.z = __bfloat16_as_ushort(tob(acc[2]));
    o.w = __bfloat16_as_ushort(tob(acc[3]));
    *(ushort4*)&apx[(size_t)n*SEM + c0] = o;
}

__global__ __launch_bounds__(256) void k_agg4(const bf16* __restrict__ cur, const float* __restrict__ We,
                      const float* __restrict__ be, const float4* __restrict__ epack,
                      const int* __restrict__ indptr, bf16* __restrict__ apx){
    int idx = blockIdx.x*256 + threadIdx.x;
    if (idx >= NN*CG) return;
    agg4_body(cur, We, be, epack, indptr, apx, idx);
}

// ---------------- dual agg: one gather pass feeds BOTH weight sets (layer-0 fusion) ----------------
__global__ __launch_bounds__(256) void k_agg4d(const bf16* __restrict__ cur,
                      const float* __restrict__ WeA, const float* __restrict__ beA,
                      const float* __restrict__ WeB, const float* __restrict__ beB,
                      const float4* __restrict__ epack, const int* __restrict__ indptr,
                      bf16* __restrict__ apxA, bf16* __restrict__ apxB){
    int idx = blockIdx.x*256 + threadIdx.x;
    if (idx >= NN*CG) return;
    int n = idx / CG, cg = idx - n*CG;
    int c0 = cg*4;
    float a0[4], a1[4], a2[4], ab[4], accA[4];
    float b0[4], b1[4], b2[4], bb[4], accB[4];
    #pragma unroll
    for (int j=0;j<4;j++){
        a0[j]=WeA[c0+j]; a1[j]=WeA[EMB+c0+j]; a2[j]=WeA[2*EMB+c0+j]; ab[j]=beA[c0+j];
        b0[j]=WeB[c0+j]; b1[j]=WeB[EMB+c0+j]; b2[j]=WeB[2*EMB+c0+j]; bb[j]=beB[c0+j];
    }
    ushort4 hs = *(const ushort4*)&cur[(size_t)n*SEM + c0];
    float fs[4] = {b2f(hs.x), b2f(hs.y), b2f(hs.z), b2f(hs.w)};
    #pragma unroll
    for (int j=0;j<4;j++){ accA[j]=fs[j]; accB[j]=fs[j]; }
    int k = indptr[n], k1 = indptr[n+1];
    for (; k+2 <= k1; k += 2){
        float4 e0 = epack[k], e1 = epack[k+1];
        int s0 = __float_as_int(e0.x), s1 = __float_as_int(e1.x);
        ushort4 ha = *(const ushort4*)&cur[(size_t)s0*SEM + c0];
        ushort4 hb = *(const ushort4*)&cur[(size_t)s1*SEM + c0];
        float fa[4] = {b2f(ha.x), b2f(ha.y), b2f(ha.z), b2f(ha.w)};
        float fb[4] = {b2f(hb.x), b2f(hb.y), b2f(hb.z), b2f(hb.w)};
        #pragma unroll
        for (int j=0;j<4;j++){
            accA[j] += fmaxf(fa[j] + e0.y*a0[j] + e0.z*a1[j] + e0.w*a2[j] + ab[j], 0.f)
                     + fmaxf(fb[j] + e1.y*a0[j] + e1.z*a1[j] + e1.w*a2[j] + ab[j], 0.f);
            accB[j] += fmaxf(fa[j] + e0.y*b0[j] + e0.z*b1[j] + e0.w*b2[j] + bb[j], 0.f)
                     + fmaxf(fb[j] + e1.y*b0[j] + e1.z*b1[j] + e1.w*b2[j] + bb[j], 0.f);
        }
    }
    if (k < k1){
        float4 e0 = epack[k];
        int s0 = __float_as_int(e0.x);
        ushort4 ha = *(const ushort4*)&cur[(size_t)s0*SEM + c0];
        float fa[4] = {b2f(ha.x), b2f(ha.y), b2f(ha.z), b2f(ha.w)};
        #pragma unroll
        for (int j=0;j<4;j++){
            accA[j] += fmaxf(fa[j] + e0.y*a0[j] + e0.z*a1[j] + e0.w*a2[j] + ab[j], 0.f);
            accB[j] += fmaxf(fa[j] + e0.y*b0[j] + e0.z*b1[j] + e0.w*b2[j] + bb[j], 0.f);
        }
    }
    ushort4 oA, oB;
    oA.x=__bfloat16_as_ushort(tob(accA[0])); oA.y=__bfloat16_as_ushort(tob(accA[1]));
    oA.z=__bfloat16_as_ushort(tob(accA[2])); oA.w=__bfloat16_as_ushort(tob(accA[3]));
    oB.x=__bfloat16_as_ushort(tob(accB[0])); oB.y=__bfloat16_as_ushort(tob(accB[1]));
    oB.z=__bfloat16_as_ushort(tob(accB[2])); oB.w=__bfloat16_as_ushort(tob(accB[3]));
    *(ushort4*)&apxA[(size_t)n*SEM + c0] = oA;
    *(ushort4*)&apxB[(size_t)n*SEM + c0] = oB;
}

// ---------------- dual-SOURCE agg (layer 1): one epack pass gathers from BOTH residual streams ----
// replaces the z-paired form: halves epack loads + address math; round-8 win (88 -> 72 us)
__global__ __launch_bounds__(256) void k_agg4dd(const bf16* __restrict__ curA, const bf16* __restrict__ curB,
                      const float* __restrict__ WeA, const float* __restrict__ beA,
                      const float* __restrict__ WeB, const float* __restrict__ beB,
                      const float4* __restrict__ epack, const int* __restrict__ indptr,
                      bf16* __restrict__ apxA, bf16* __restrict__ apxB){
    int idx = blockIdx.x*256 + threadIdx.x;
    if (idx >= NN*CG) return;
    int n = idx / CG, cg = idx - n*CG;
    int c0 = cg*4;
    float a0[4], a1[4], a2[4], ab[4], accA[4];
    float b0[4], b1[4], b2[4], bb[4], accB[4];
    #pragma unroll
    for (int j=0;j<4;j++){
        a0[j]=WeA[c0+j]; a1[j]=WeA[EMB+c0+j]; a2[j]=WeA[2*EMB+c0+j]; ab[j]=beA[c0+j];
        b0[j]=WeB[c0+j]; b1[j]=WeB[EMB+c0+j]; b2[j]=WeB[2*EMB+c0+j]; bb[j]=beB[c0+j];
    }
    ushort4 hsA = *(const ushort4*)&curA[(size_t)n*SEM + c0];
    ushort4 hsB = *(const ushort4*)&curB[(size_t)n*SEM + c0];
    accA[0]=b2f(hsA.x); accA[1]=b2f(hsA.y); accA[2]=b2f(hsA.z); accA[3]=b2f(hsA.w);
    accB[0]=b2f(hsB.x); accB[1]=b2f(hsB.y); accB[2]=b2f(hsB.z); accB[3]=b2f(hsB.w);
    int k = indptr[n], k1 = indptr[n+1];
    for (; k+2 <= k1; k += 2){
        float4 e0 = epack[k], e1 = epack[k+1];
        int s0 = __float_as_int(e0.x), s1 = __float_as_int(e1.x);
        ushort4 ha = *(const ushort4*)&curA[(size_t)s0*SEM + c0];
        ushort4 hb = *(const ushort4*)&curA[(size_t)s1*SEM + c0];
        ushort4 hc = *(const ushort4*)&curB[(size_t)s0*SEM + c0];
        ushort4 hd = *(const ushort4*)&curB[(size_t)s1*SEM + c0];
        float fa[4] = {b2f(ha.x), b2f(ha.y), b2f(ha.z), b2f(ha.w)};
        float fb[4] = {b2f(hb.x), b2f(hb.y), b2f(hb.z), b2f(hb.w)};
        float fc[4] = {b2f(hc.x), b2f(hc.y), b2f(hc.z), b2f(hc.w)};
        float fd[4] = {b2f(hd.x), b2f(hd.y), b2f(hd.z), b2f(hd.w)};
        #pragma unroll
        for (int j=0;j<4;j++){
            accA[j] += fmaxf(fa[j] + e0.y*a0[j] + e0.z*a1[j] + e0.w*a2[j] + ab[j], 0.f)
                     + fmaxf(fb[j] + e1.y*a0[j] + e1.z*a1[j] + e1.w*a2[j] + ab[j], 0.f);
            accB[j] += fmaxf(fc[j] + e0.y*b0[j] + e0.z*b1[j] + e0.w*b2[j] + bb[j], 0.f)
                     + fmaxf(fd[j] + e1.y*b0[j] + e1.z*b1[j] + e1.w*b2[j] + bb[j], 0.f);
        }
    }
    if (k < k1){
        float4 e0 = epack[k];
        int s0 = __float_as_int(e0.x);
        ushort4 ha = *(const ushort4*)&curA[(size_t)s0*SEM + c0];
        ushort4 hc = *(const ushort4*)&curB[(size_t)s0*SEM + c0];
        float fa[4] = {b2f(ha.x), b2f(ha.y), b2f(ha.z), b2f(ha.w)};
        float fc[4] = {b2f(hc.x), b2f(hc.y), b2f(hc.z), b2f(hc.w)};
        #pragma unroll
        for (int j=0;j<4;j++){
            accA[j] += fmaxf(fa[j] + e0.y*a0[j] + e0.z*a1[j] + e0.w*a2[j] + ab[j], 0.f);
            accB[j] += fmaxf(fc[j] + e0.y*b0[j] + e0.z*b1[j] + e0.w*b2[j] + bb[j], 0.f);
        }
    }
    ushort4 oA, oB;
    oA.x=__bfloat16_as_ushort(tob(accA[0])); oA.y=__bfloat16_as_ushort(tob(accA[1]));
    oA.z=__bfloat16_as_ushort(tob(accA[2])); oA.w=__bfloat16_as_ushort(tob(accA[3]));
    oB.x=__bfloat16_as_ushort(tob(accB[0])); oB.y=__bfloat16_as_ushort(tob(accB[1]));
    oB.z=__bfloat16_as_ushort(tob(accB[2])); oB.w=__bfloat16_as_ushort(tob(accB[3]));
    *(ushort4*)&apxA[(size_t)n*SEM + c0] = oA;
    *(ushort4*)&apxB[(size_t)n*SEM + c0] = oB;
}

// ---------------- MFMA bf16 GEMM body (BN=128): reg-staged dbuf K-loop ----------------
// Reg-staging (not global_load_lds): register loads stay in flight across the barrier (round-1
// lesson). Used for N=600 GEMMs, gatepair, simhead.
__device__ __forceinline__ void gemm_body(const bf16* __restrict__ A, const bf16* __restrict__ Bt,
        const float* __restrict__ bias, const bf16* __restrict__ R, bf16* __restrict__ C,
        int M, int N, int Kp, int ldc, int relu_out, short* lds, int m0, int n0){
    short* Ct = lds;
    const int CS = 136;
    int tid = threadIdx.x;
    int wave = tid >> 6, lane = tid & 63;
    int wm = wave >> 1, wn = wave & 1;

    int srow = tid >> 1;
    int sq   = (tid & 1) * 2;
    int grA = min(m0 + srow, M-1);
    int grB = min(n0 + srow, N-1);
    const bf16* pA = A  + (size_t)grA*Kp + sq*8;
    const bf16* pB = Bt + (size_t)grB*Kp + sq*8;
    int aoff0 = ((srow>>4)*64 +  sq   *16 + (srow&15))*8;
    int aoff1 = ((srow>>4)*64 + (sq+1)*16 + (srow&15))*8;

    f32x4 acc[4][4];
    #pragma unroll
    for (int i=0;i<4;i++){
        #pragma unroll
        for (int j=0;j<4;j++) acc[i][j] = (f32x4){0.f,0.f,0.f,0.f};
    }

    int KC = Kp >> 5;
    uint4 ra0 = *(const uint4*)(pA);
    uint4 ra1 = *(const uint4*)(pA + 8);
    uint4 rb0 = *(const uint4*)(pB);
    uint4 rb1 = *(const uint4*)(pB + 8);
    *(uint4*)(lds + aoff0)        = ra0;
    *(uint4*)(lds + aoff1)        = ra1;
    *(uint4*)(lds + 4096 + aoff0) = rb0;
    *(uint4*)(lds + 4096 + aoff1) = rb1;
    __syncthreads();
    if (KC > 1){
        ra0 = *(const uint4*)(pA + 32); ra1 = *(const uint4*)(pA + 40);
        rb0 = *(const uint4*)(pB + 32); rb1 = *(const uint4*)(pB + 40);
    }

    for (int kc=0; kc<KC; ++kc){
        short* cbuf = lds + (kc & 1)*8192;
        short* nbuf = lds + ((kc+1) & 1)*8192;
        if (kc+1 < KC){
            *(uint4*)(nbuf + aoff0)        = ra0;
            *(uint4*)(nbuf + aoff1)        = ra1;
            *(uint4*)(nbuf + 4096 + aoff0) = rb0;
            *(uint4*)(nbuf + 4096 + aoff1) = rb1;
            if (kc+2 < KC){
                const bf16* qA = pA + (kc+2)*32;
                const bf16* qB = pB + (kc+2)*32;
                ra0 = *(const uint4*)(qA); ra1 = *(const uint4*)(qA+8);
                rb0 = *(const uint4*)(qB); rb1 = *(const uint4*)(qB+8);
            }
        }
        bf16x8 af[4], bfr[4];
        #pragma unroll
        for (int i=0;i<4;i++) af[i]  = *(const bf16x8*)(cbuf + ((wm*4+i)*64 + lane)*8);
        #pragma unroll
        for (int j=0;j<4;j++) bfr[j] = *(const bf16x8*)(cbuf + 4096 + ((wn*4+j)*64 + lane)*8);
        #pragma unroll
        for (int i=0;i<4;i++){
            #pragma unroll
            for (int j=0;j<4;j++)
                acc[i][j] = __builtin_amdgcn_mfma_f32_16x16x32_bf16(af[i], bfr[j], acc[i][j], 0, 0, 0);
        }
        __syncthreads();
    }

    int lq = lane >> 4, lr = lane & 15;
    #pragma unroll
    for (int i=0;i<4;i++){
        int rl = (wm*4+i)*16 + lq*4;
        #pragma unroll
        for (int j=0;j<4;j++){
            int cl = (wn*4+j)*16 + lr;
            float bv = bias[min(n0+cl, N-1)];
            #pragma unroll
            for (int r=0;r<4;r++){
                float v = acc[i][j][r] + bv;
                if (relu_out) v = fmaxf(v, 0.f);
                Ct[(rl+r)*CS + cl] = (short)__bfloat16_as_ushort(tob(v));
            }
        }
    }
    __syncthreads();
    #pragma unroll
    for (int p=0;p<8;p++){
        int rl = p*16 + (tid>>4);
        int cl = (tid&15)*8;
        int row = m0 + rl, col = n0 + cl;
        if (row < M && col < N){
            union { short s8[8]; uint4 v; } u;
            u.v = *(uint4*)&Ct[rl*CS + cl];
            if (R){
                const bf16* rp = &R[(size_t)row*ldc + col];
                #pragma unroll
                for (int e=0;e<8;e++){
                    float v = b2f((unsigned short)u.s8[e]) + tof(rp[e]);
                    u.s8[e] = (short)__bfloat16_as_ushort(tob(v));
                }
            }
            *(uint4*)&C[(size_t)row*ldc + col] = u.v;
        }
    }
}

__global__ __launch_bounds__(256) void k_gemm2(const bf16* __restrict__ A, const bf16* __restrict__ Bt,
        const float* __restrict__ bias, const bf16* __restrict__ R, bf16* __restrict__ C,
        int M, int N, int Kp, int ldc, int relu_out){
    __shared__ __align__(16) char ldsbuf[34816];
    int nwg = gridDim.x*gridDim.y;
    int w = xcd_swz(blockIdx.y*gridDim.x + blockIdx.x, nwg);
    gemm_body(A, Bt, bias, R, C, M, N, Kp, ldc, relu_out, (short*)ldsbuf,
              (w/gridDim.x)*128, (w%gridDim.x)*128);
}

__global__ __launch_bounds__(256) void k_gemm2z(
        const bf16* __restrict__ A0, const bf16* __restrict__ A1,
        const bf16* __restrict__ Bt0, const bf16* __restrict__ Bt1,
        const float* __restrict__ bias0, const float* __restrict__ bias1,
        const bf16* __restrict__ R0, const bf16* __restrict__ R1,
        bf16* __restrict__ C0, bf16* __restrict__ C1,
        int M, int N, int Kp, int ldc, int relu0, int relu1){
    __shared__ __align__(16) char ldsbuf[34816];
    int nwg = gridDim.x*gridDim.y;
    int w = xcd_swz(blockIdx.y*gridDim.x + blockIdx.x, nwg);
    int m0 = (w/gridDim.x)*128, n0 = (w%gridDim.x)*128;
    if (blockIdx.z == 0) gemm_body(A0, Bt0, bias0, R0, C0, M, N, Kp, ldc, relu0, (short*)ldsbuf, m0, n0);
    else                 gemm_body(A1, Bt1, bias1, R1, C1, M, N, Kp, ldc, relu1, (short*)ldsbuf, m0, n0);
}

// ---------------- BN=160 GEMM body: for N=300 outputs ----------------
// vs BN=128 (3 col-tiles, 384 cols): 2 col-tiles -> A re-fetched 2x not 3x AND cols 320 not 384.
// LDS per buffer: A 4096 + B 5120 shorts (stride 9216 shorts); Ct 128x168 = 43008 B total.
__device__ __forceinline__ void gemm160_body(const bf16* __restrict__ A, const bf16* __restrict__ Bt,
        const float* __restrict__ bias, const bf16* __restrict__ R, bf16* __restrict__ C,
        int M, int N, int Kp, int ldc, int relu_out, short* lds, int m0, int n0){
    short* Ct = lds;
    const int CS = 168;
    const int BUF = 9216;   // shorts per dbuf half
    int tid = threadIdx.x;
    int wave = tid >> 6, lane = tid & 63;
    int wm = wave >> 1, wn = wave & 1;

    // A staging: 512 16B chunks, 2/thread
    int srow = tid >> 1;
    int sq   = (tid & 1) * 2;
    int grA = min(m0 + srow, M-1);
    const bf16* pA = A + (size_t)grA*Kp + sq*8;
    int aoff0 = ((srow>>4)*64 +  sq   *16 + (srow&15))*8;
    int aoff1 = ((srow>>4)*64 + (sq+1)*16 + (srow&15))*8;

    // B staging: 640 16B chunks: tid, tid+256, and tid+512 for tid<128 (wave-uniform split)
    int cB0 = tid, cB1 = tid + 256, cB2 = tid + 512;
    int br0 = cB0>>2, bq0 = cB0&3;
    int br1 = cB1>>2, bq1 = cB1&3;
    int br2 = cB2>>2, bq2 = cB2&3;
    const bf16* pB0 = Bt + (size_t)min(n0+br0, N-1)*Kp + bq0*8;
    const bf16* pB1 = Bt + (size_t)min(n0+br1, N-1)*Kp + bq1*8;
    const bf16* pB2 = Bt + (size_t)min(n0+br2, N-1)*Kp + bq2*8;
    int boff0 = 4096 + ((br0>>4)*64 + bq0*16 + (br0&15))*8;
    int boff1 = 4096 + ((br1>>4)*64 + bq1*16 + (br1&15))*8;
    int boff2 = 4096 + ((br2>>4)*64 + bq2*16 + (br2&15))*8;
    bool b3 = (tid < 128);

    f32x4 acc[4][5];
    #pragma unroll
    for (int i=0;i<4;i++){
        #pragma unroll
        for (int j=0;j<5;j++) acc[i][j] = (f32x4){0.f,0.f,0.f,0.f};
    }

    int KC = Kp >> 5;
    uint4 ra0 = *(const uint4*)(pA);
    uint4 ra1 = *(const uint4*)(pA + 8);
    uint4 rb0 = *(const uint4*)(pB0);
    uint4 rb1 = *(const uint4*)(pB1);
    uint4 rb2 = {0,0,0,0};
    if (b3) rb2 = *(const uint4*)(pB2);
    *(uint4*)(lds + aoff0) = ra0;
    *(uint4*)(lds + aoff1) = ra1;
    *(uint4*)(lds + boff0) = rb0;
    *(uint4*)(lds + boff1) = rb1;
    if (b3) *(uint4*)(lds + boff2) = rb2;
    __syncthreads();
    if (KC > 1){
        ra0 = *(const uint4*)(pA + 32);  ra1 = *(const uint4*)(pA + 40);
        rb0 = *(const uint4*)(pB0 + 32); rb1 = *(const uint4*)(pB1 + 32);
        if (b3) rb2 = *(const uint4*)(pB2 + 32);
    }

    for (int kc=0; kc<KC; ++kc){
        short* cbuf = lds + (kc & 1)*BUF;
        short* nbuf = lds + ((kc+1) & 1)*BUF;
        if (kc+1 < KC){
            *(uint4*)(nbuf + aoff0) = ra0;
            *(uint4*)(nbuf + aoff1) = ra1;
            *(uint4*)(nbuf + boff0) = rb0;
            *(uint4*)(nbuf + boff1) = rb1;
            if (b3) *(uint4*)(nbuf + boff2) = rb2;
            if (kc+2 < KC){
                const bf16* qA = pA + (kc+2)*32;
                ra0 = *(const uint4*)(qA); ra1 = *(const uint4*)(qA+8);
                rb0 = *(const uint4*)(pB0 + (kc+2)*32);
                rb1 = *(const uint4*)(pB1 + (kc+2)*32);
                if (b3) rb2 = *(const uint4*)(pB2 + (kc+2)*32);
            }
        }
        bf16x8 af[4], bfr[5];
        #pragma unroll
        for (int i=0;i<4;i++) af[i]  = *(const bf16x8*)(cbuf + ((wm*4+i)*64 + lane)*8);
        #pragma unroll
        for (int j=0;j<5;j++) bfr[j] = *(const bf16x8*)(cbuf + 4096 + ((wn*5+j)*64 + lane)*8);
        #pragma unroll
        for (int i=0;i<4;i++){
            #pragma unroll
            for (int j=0;j<5;j++)
                acc[i][j] = __builtin_amdgcn_mfma_f32_16x16x32_bf16(af[i], bfr[j], acc[i][j], 0, 0, 0);
        }
        __syncthreads();
    }

    int lq = lane >> 4, lr = lane & 15;
    #pragma unroll
    for (int i=0;i<4;i++){
        int rl = (wm*4+i)*16 + lq*4;
        #pragma unroll
        for (int j=0;j<5;j++){
            int cl = (wn*5+j)*16 + lr;
            float bv = bias[min(n0+cl, N-1)];
            #pragma unroll
            for (int r=0;r<4;r++){
                float v = acc[i][j][r] + bv;
                if (relu_out) v = fmaxf(v, 0.f);
                Ct[(rl+r)*CS + cl] = (short)__bfloat16_as_ushort(tob(v));
            }
        }
    }
    __syncthreads();
    // writeout: 128 rows x 20 col-chunks(8) = 2560 chunks, 10/thread
    #pragma unroll
    for (int p=0;p<10;p++){
        int c = p*256 + tid;
        int row = c / 20, colc = c - (c/20)*20;
        int grow = m0 + row, gcol = n0 + colc*8;
        if (grow < M && gcol < N){
            union { short s8[8]; uint4 v; } u;
            u.v = *(uint4*)&Ct[row*CS + colc*8];
            if (R){
                const bf16* rp = &R[(size_t)grow*ldc + gcol];
                #pragma unroll
                for (int e=0;e<8;e++){
                    float v = b2f((unsigned short)u.s8[e]) + tof(rp[e]);
                    u.s8[e] = (short)__bfloat16_as_ushort(tob(v));
                }
            }
            *(uint4*)&C[(size_t)grow*ldc + gcol] = u.v;
        }
    }
}

__global__ __launch_bounds__(256) void k_gemm160(const bf16* __restrict__ A, const bf16* __restrict__ Bt,
        const float* __restrict__ bias, const bf16* __restrict__ R, bf16* __restrict__ C,
        int M, int N, int Kp, int ldc, int relu_out){
    __shared__ __align__(16) char ldsbuf[43008];
    int nwg = gridDim.x*gridDim.y;
    int w = xcd_swz(blockIdx.y*gridDim.x + blockIdx.x, nwg);
    gemm160_body(A, Bt, bias, R, C, M, N, Kp, ldc, relu_out, (short*)ldsbuf,
                 (w/gridDim.x)*128, (w%gridDim.x)*160);
}

__global__ __launch_bounds__(256) void k_gemm160z(
        const bf16* __restrict__ A0, const bf16* __restrict__ A1,
        const bf16* __restrict__ Bt0, const bf16* __restrict__ Bt1,
        const float* __restrict__ bias0, const float* __restrict__ bias1,
        const bf16* __restrict__ R0, const bf16* __restrict__ R1,
        bf16* __restrict__ C0, bf16* __restrict__ C1,
        int M, int N, int Kp, int ldc, int relu0, int relu1){
    __shared__ __align__(16) char ldsbuf[43008];
    int nwg = gridDim.x*gridDim.y;
    int w = xcd_swz(blockIdx.y*gridDim.x + blockIdx.x, nwg);
    int m0 = (w/gridDim.x)*128, n0 = (w%gridDim.x)*160;
    if (blockIdx.z == 0) gemm160_body(A0, Bt0, bias0, R0, C0, M, N, Kp, ldc, relu0, (short*)ldsbuf, m0, n0);
    else                 gemm160_body(A1, Bt1, bias1, R1, C1, M, N, Kp, ldc, relu1, (short*)ldsbuf, m0, n0);
}

// enc-l2 g2 (BN160) + gate finisher in one dispatch: [0,470) gemm blocks, [470,588) gate blocks
__global__ __launch_bounds__(256) void k_g160gate(
        const bf16* __restrict__ A, const bf16* __restrict__ Bt, const float* __restrict__ bias,
        const bf16* __restrict__ R, bf16* __restrict__ C,
        const float* __restrict__ glogit, const float* __restrict__ bg2,
        const float* __restrict__ gumbel, float* __restrict__ gate){
    __shared__ __align__(16) char ldsbuf[43008];
    int bid = blockIdx.x;
    if (bid < 470){
        int w = xcd_swz(bid, 470);
        gemm160_body(A, Bt, bias, R, C, NN, EMB, SHID, SEM, 1, (short*)ldsbuf,
                     (w>>1)*128, (w&1)*160);
    } else {
        int i = (bid-470)*256 + threadIdx.x;
        if (i >= NN) return;
        float l0 = glogit[2*i]   + bg2[0] + gumbel[2*i];
        float l1 = glogit[2*i+1] + bg2[1] + gumbel[2*i+1];
        float m = fmaxf(l0, l1);
        float e0 = expf(l0-m), e1 = expf(l1-m);
        gate[i] = e1/(e0+e1);
    }
}

// ---------------- gate GEMM: logits from acc registers, no C write ----------------
// logit[row][t] = sum_col relu(acc+bias) * Wg2[col*2+t]; 16-lane shfl reduce + atomicAdd.
__device__ __forceinline__ void gate_gemm_body(const bf16* __restrict__ A, const bf16* __restrict__ Bt,
        const float* __restrict__ bias, const float* __restrict__ Wg2, float* __restrict__ glogit,
        int M, int N, int Kp, short* lds, int m0, int n0){
    int tid = threadIdx.x;
    int wave = tid >> 6, lane = tid & 63;
    int wm = wave >> 1, wn = wave & 1;

    int srow = tid >> 1;
    int sq   = (tid & 1) * 2;
    int grA = min(m0 + srow, M-1);
    int grB = min(n0 + srow, N-1);
    const bf16* pA = A  + (size_t)grA*Kp + sq*8;
    const bf16* pB = Bt + (size_t)grB*Kp + sq*8;
    int aoff0 = ((srow>>4)*64 +  sq   *16 + (srow&15))*8;
    int aoff1 = ((srow>>4)*64 + (sq+1)*16 + (srow&15))*8;

    f32x4 acc[4][4];
    #pragma unroll
    for (int i=0;i<4;i++){
        #pragma unroll
        for (int j=0;j<4;j++) acc[i][j] = (f32x4){0.f,0.f,0.f,0.f};
    }

    int KC = Kp >> 5;
    uint4 ra0 = *(const uint4*)(pA);
    uint4 ra1 = *(const uint4*)(pA + 8);
    uint4 rb0 = *(const uint4*)(pB);
    uint4 rb1 = *(const uint4*)(pB + 8);
    *(uint4*)(lds + aoff0)        = ra0;
    *(uint4*)(lds + aoff1)        = ra1;
    *(uint4*)(lds + 4096 + aoff0) = rb0;
    *(uint4*)(lds + 4096 + aoff1) = rb1;
    __syncthreads();
    if (KC > 1){
        ra0 = *(const uint4*)(pA + 32); ra1 = *(const uint4*)(pA + 40);
        rb0 = *(const uint4*)(pB + 32); rb1 = *(const uint4*)(pB + 40);
    }

    for (int kc=0; kc<KC; ++kc){
        short* cbuf = lds + (kc & 1)*8192;
        short* nbuf = lds + ((kc+1) & 1)*8192;
        if (kc+1 < KC){
            *(uint4*)(nbuf + aoff0)        = ra0;
            *(uint4*)(nbuf + aoff1)        = ra1;
            *(uint4*)(nbuf + 4096 + aoff0) = rb0;
            *(uint4*)(nbuf + 4096 + aoff1) = rb1;
            if (kc+2 < KC){
                const bf16* qA = pA + (kc+2)*32;
                const bf16* qB = pB + (kc+2)*32;
                ra0 = *(const uint4*)(qA); ra1 = *(const uint4*)(qA+8);
                rb0 = *(const uint4*)(qB); rb1 = *(const uint4*)(qB+8);
            }
        }
        bf16x8 af[4], bfr[4];
        #pragma unroll
        for (int i=0;i<4;i++) af[i]  = *(const bf16x8*)(cbuf + ((wm*4+i)*64 + lane)*8);
        #pragma unroll
        for (int j=0;j<4;j++) bfr[j] = *(const bf16x8*)(cbuf + 4096 + ((wn*4+j)*64 + lane)*8);
        #pragma unroll
        for (int i=0;i<4;i++){
            #pragma unroll
            for (int j=0;j<4;j++)
                acc[i][j] = __builtin_amdgcn_mfma_f32_16x16x32_bf16(af[i], bfr[j], acc[i][j], 0, 0, 0);
        }
        __syncthreads();
    }

    int lq = lane >> 4, lr = lane & 15;
    #pragma unroll
    for (int i=0;i<4;i++){
        #pragma unroll
        for (int r=0;r<4;r++){
            int row = m0 + (wm*4+i)*16 + lq*4 + r;
            float p0 = 0.f, p1 = 0.f;
            #pragma unroll
            for (int j=0;j<4;j++){
                int cl = (wn*4+j)*16 + lr;
                int col = n0 + cl;
                float v = fmaxf(acc[i][j][r] + bias[min(col, N-1)], 0.f);
                if (col < N){ p0 += v * Wg2[col*2]; p1 += v * Wg2[col*2+1]; }
            }
            #pragma unroll
            for (int m=1; m<16; m<<=1){ p0 += __shfl_xor(p0, m); p1 += __shfl_xor(p1, m); }
            if (lr == 0 && row < M){
                atomicAdd(&glogit[row*2],   p0);
                atomicAdd(&glogit[row*2+1], p1);
            }
        }
    }
}

// hetero pair: [0,1175) gate-gemm (cur_r @ Wg1 -> logits), [1175,2350) enc-l2 g1 (normal)
__global__ __launch_bounds__(256) void k_gatepair(
        const bf16* __restrict__ Ag, const bf16* __restrict__ Btg, const float* __restrict__ bg,
        const float* __restrict__ Wg2, float* __restrict__ glogit,
        const bf16* __restrict__ A1, const bf16* __restrict__ Bt1, const float* __restrict__ b1,
        bf16* __restrict__ C1){
    __shared__ __align__(16) char ldsbuf[34816];
    int bid = blockIdx.x;
    if (bid < 1175){
        int w = xcd_swz(bid, 1175);
        gate_gemm_body(Ag, Btg, bg, Wg2, glogit, NN, HID, SEM, (short*)ldsbuf,
                       (w/5)*128, (w%5)*128);
    } else {
        int w = xcd_swz(bid - 1175, 1175);
        gemm_body(A1, Bt1, b1, nullptr, C1, NN, HID, SEM, SHID, 1, (short*)ldsbuf,
                  (w/5)*128, (w%5)*128);
    }
}

// ---------------- sim machinery (device) ----------------
__device__ __forceinline__ void stage_tile(const short* __restrict__ P, int RB, int K, int r0, int k0,
                                           short (*lds)[64][8], int tid){
    #pragma unroll
    for (int s=0;s<2;s++){
        int seg = tid*2+s;
        int row = seg>>2, q = seg&3;
        int gr = r0 + row;
        int gk = k0 + q*8;
        union { short s8[8]; uint4 v; } u;
        if (gr < RB && gk + 8 <= K){
            const uint2* p = (const uint2*)(P + (size_t)gr*K + gk);
            uint2 lo = p[0], hi = p[1];
            u.v.x = lo.x; u.v.y = lo.y; u.v.z = hi.x; u.v.w = hi.y;
        } else {
            #pragma unroll
            for (int j=0;j<8;j++){
                int kk = gk + j;
                u.s8[j] = (gr < RB && kk < K) ? P[(size_t)gr*K + kk] : (short)0;
            }
        }
        *(uint4*)&lds[row>>4][q*16 + (row&15)][0] = u.v;
    }
}

// sim_cp rowsums: S[i] += sum_j exp((hr_i.henv_j)*5/(na_i*nc_j+1e-8)); matrix never materialized
__device__ __forceinline__ void sim_body(const bf16* __restrict__ A, const bf16* __restrict__ Bt,
                      const float* __restrict__ na, const float* __restrict__ nc, float* __restrict__ S,
                      char* ldsraw){
    short (*Asl)[64][8] = (short(*)[64][8])ldsraw;
    short (*Bsl)[64][8] = (short(*)[64][8])(ldsraw + 8192);
    int tid = threadIdx.x;
    int wave = tid >> 6, lane = tid & 63;
    int wm = wave >> 1, wn = wave & 1;
    int m0 = blockIdx.y*128, n0 = blockIdx.x*128;
    f32x4 acc[4][4];
    #pragma unroll
    for (int i=0;i<4;i++){
        #pragma unroll
        for (int j=0;j<4;j++) acc[i][j] = (f32x4){0.f,0.f,0.f,0.f};
    }
    for (int k0=0; k0<SEM; k0+=32){
        stage_tile((const short*)A,  NG, SEM, m0, k0, Asl, tid);
        stage_tile((const short*)Bt, NG, SEM, n0, k0, Bsl, tid);
        __syncthreads();
        bf16x8 af[4], bfr[4];
        #pragma unroll
        for (int i=0;i<4;i++) af[i]  = *(const bf16x8*)&Asl[wm*4+i][lane][0];
        #pragma unroll
        for (int j=0;j<4;j++) bfr[j] = *(const bf16x8*)&Bsl[wn*4+j][lane][0];
        #pragma unroll
        for (int i=0;i<4;i++){
            #pragma unroll
            for (int j=0;j<4;j++)
                acc[i][j] = __builtin_amdgcn_mfma_f32_16x16x32_bf16(af[i], bfr[j], acc[i][j], 0, 0, 0);
        }
        __syncthreads();
    }
    int lq = lane >> 4, lr = lane & 15;
    #pragma unroll
    for (int i=0;i<4;i++){
        #pragma unroll
        for (int r=0;r<4;r++){
            int row = m0 + (wm*4+i)*16 + lq*4 + r;
            float nar = na[min(row, NG-1)];
            float rsum = 0.f;
            #pragma unroll
            for (int j=0;j<4;j++){
                int col = n0 + (wn*4+j)*16 + lr;
                float ncj = nc[min(col, NG-1)];
                float e = expf(acc[i][j][r] * 5.0f / (nar*ncj + 1e-8f));
                if (row < NG && col < NG) rsum += e;
            }
            #pragma unroll
            for (int m=1; m<16; m<<=1) rsum += __shfl_xor(rsum, m);
            if (lr == 0 && row < NG) atomicAdd(&S[row], rsum);
        }
    }
}

// fat kernel: z=0 -> sim rowsums (grid 12x12), z=1 -> head GEMM (grid 5x24)
__global__ __launch_bounds__(256) void k_simhead(const bf16* __restrict__ hrb, const bf16* __restrict__ henvb,
        const float* __restrict__ na, const float* __restrict__ nc, float* __restrict__ Ssum,
        const bf16* __restrict__ Pbuf, const bf16* __restrict__ wtp1, const float* __restrict__ bp1,
        bf16* __restrict__ hidP){
    __shared__ __align__(16) char ldsbuf[34816];
    if (blockIdx.z == 0){
        if (blockIdx.x >= 12 || blockIdx.y >= 12) return;
        sim_body(hrb, henvb, na, nc, Ssum, ldsbuf);
    } else {
        if (blockIdx.x >= 5) return;
        gemm_body(Pbuf, wtp1, bp1, nullptr, hidP, 2*NG, HID, SEM, SHID, 1, (short*)ldsbuf,
                  blockIdx.y*128, blockIdx.x*128);
    }
}

// ---------------- fused pooling + mean + norms + P top half (one block per graph) ----------------
// sums stay in registers: kills the sumh/sumgh round-trip and the k_meannorm dispatch
__global__ __launch_bounds__(320) void k_poolmean(const bf16* __restrict__ h, const float* __restrict__ gate,
                      const int* __restrict__ gstart, float* __restrict__ hr, float* __restrict__ henv,
                      bf16* __restrict__ hrb, bf16* __restrict__ henvb, bf16* __restrict__ P,
                      float* __restrict__ na, float* __restrict__ nc, float* __restrict__ pos,
                      float* __restrict__ rnum, float* __restrict__ cntf, float* __restrict__ Ssum){
    int g = blockIdx.x, c = threadIdx.x;
    int n0 = gstart[g], n1 = gstart[g+1];
    float sh=0.f, sg=0.f, sgate=0.f;
    if (c < EMB){
        for (int n=n0;n<n1;n++){
            float v = tof(h[(size_t)n*SEM+c]);
            float gt = gate[n];
            sh += v; sg += gt*v;
            if (c==0) sgate += gt;
        }
    }
    float cnt = (float)(n1-n0);
    float inv = 1.f / fmaxf(cnt, 1.f);
    float r=0.f, e=0.f, o=0.f;
    int idx = g*SEM + c;
    if (c < EMB){
        int off = g*EMB + c;
        r = sg*inv; e = (sh-sg)*inv; o = sh*inv;
        hr[off] = r; henv[off] = e;
        hrb[idx] = tob(r); henvb[idx] = tob(e); P[idx] = tob(r);
        if (c==0){ rnum[g] = sgate; cntf[g] = cnt; }
    } else {
        hrb[idx] = tob(0.f); henvb[idx] = tob(0.f); P[idx] = tob(0.f);   // zero pads (B-operands!)
        if (c == 319) Ssum[g] = 0.f;
    }
    float srr=r*r, soo=o*o, see=e*e, sro=r*o;
    #pragma unroll
    for (int off=32; off>0; off>>=1){
        srr += __shfl_down(srr,off); soo += __shfl_down(soo,off);
        see += __shfl_down(see,off); sro += __shfl_down(sro,off);
    }
    __shared__ float ws[4][5];
    int wv = c >> 6, ln = c & 63;
    if (ln == 0){ ws[0][wv]=srr; ws[1][wv]=soo; ws[2][wv]=see; ws[3][wv]=sro; }
    __syncthreads();
    if (c == 0){
        float a=0.f,b=0.f,c2=0.f,d=0.f;
        #pragma unroll
        for (int i=0;i<5;i++){ a+=ws[0][i]; b+=ws[1][i]; c2+=ws[2][i]; d+=ws[3][i]; }
        float sa = sqrtf(a), sb = sqrtf(b), sc = sqrtf(c2);
        na[g] = sa; nc[g] = sc;
        pos[g] = expf(d/(sa*sb + 1e-8f) * 5.0f);
    }
}

// P bottom half: needs OTHER graphs' henv (perm) -> separate dispatch after k_poolmean
__global__ __launch_bounds__(256) void k_pbuild2(const float* __restrict__ hr, const float* __restrict__ henv,
                      const int* __restrict__ perm, bf16* __restrict__ P){
    int idx = blockIdx.x*256 + threadIdx.x;
    if (idx >= NG*SEM) return;
    int g = idx / SEM, c = idx - g*SEM;
    P[(size_t)(NG+g)*SEM + c] = (c < EMB)
        ? tob(hr[g*EMB+c] + henv[(size_t)perm[g]*EMB + c])
        : tob(0.f);
}

// pred (blocks 0..749) + loss (block 750) fused: all loss inputs ready before this dispatch
__global__ __launch_bounds__(256) void k_predloss(const bf16* __restrict__ hidP, const float* __restrict__ Wp2,
                      const float* __restrict__ bp2, const float* __restrict__ cntf,
                      const float* __restrict__ rnum, const float* __restrict__ pos,
                      const float* __restrict__ S, float* __restrict__ out){
    if (blockIdx.x == 750){
        __shared__ float ra[256], rb[256];
        int t = threadIdx.x;
        float a=0.f, b=0.f;
        for (int g=t; g<NG; g+=256){
            float r = rnum[g] + 1e-8f;
            float e = (cntf[g] - rnum[g]) + 1e-8f;
            a += fabsf(r/(r+e) - 0.4f);
            float p = pos[g];
            b += -logf(p/(S[g]+p));
        }
        ra[t]=a; rb[t]=b; __syncthreads();
        for (int off=128; off>0; off>>=1){ if (t<off){ ra[t]+=ra[t+off]; rb[t]+=rb[t+off]; } __syncthreads(); }
        if (t==0){
            out[2*NG*NTASK]   = ra[0]/NG;
            out[2*NG*NTASK+1] = rb[0]/NG;
        }
        return;
    }
    int r = blockIdx.x*4 + (threadIdx.x >> 6);
    int lane = threadIdx.x & 63;
    if (r >= 2*NG) return;
    float acc[NTASK];
    #pragma unroll
    for (int t=0;t<NTASK;t++) acc[t] = 0.f;
    for (int i=lane;i<HID;i+=64){
        float h = tof(hidP[(size_t)r*SHID+i]);
        const float4* wp = (const float4*)&Wp2[i*NTASK];
        float4 wa = wp[0], wb = wp[1], wc = wp[2];
        acc[0]+=h*wa.x; acc[1]+=h*wa.y; acc[2]+=h*wa.z; acc[3]+=h*wa.w;
        acc[4]+=h*wb.x; acc[5]+=h*wb.y; acc[6]+=h*wb.z; acc[7]+=h*wb.w;
        acc[8]+=h*wc.x; acc[9]+=h*wc.y; acc[10]+=h*wc.z; acc[11]+=h*wc.w;
    }
    #pragma unroll
    for (int t=0;t<NTASK;t++){
        for (int off=32; off>0; off>>=1) acc[t] += __shfl_down(acc[t], off);
    }
    if (lane==0){
        float* dst = (r < NG) ? &out[NG*NTASK + r*NTASK] : &out[(r-NG)*NTASK];
        #pragma unroll
        for (int t=0;t<NTASK;t++) dst[t] = acc[t] + bp2[t];
    }
}

extern "C" void kernel_launch(void* const* d_in, const int* in_sizes, int n_in,
                              void* d_out, int out_size, void* d_ws, size_t ws_size,
                              hipStream_t stream) {
    const float* x      = (const float*)d_in[0];
    const float* eattr  = (const float*)d_in[1];
    const int*   eidx   = (const int*)d_in[2];
    const int*   batch  = (const int*)d_in[3];
    const float* gumbel = (const float*)d_in[4];
    const int*   perm   = (const int*)d_in[5];
    const float* W_enc  = (const float*)d_in[6];
    const float* b_enc  = (const float*)d_in[7];
    const float* We_g   = (const float*)d_in[8];
    const float* be_g   = (const float*)d_in[9];
    const float* W1_g   = (const float*)d_in[10];
    const float* b1_g   = (const float*)d_in[11];
    const float* W2_g   = (const float*)d_in[12];
    const float* b2_g   = (const float*)d_in[13];
    const float* We_r   = (const float*)d_in[14];
    const float* be_r   = (const float*)d_in[15];
    const float* W1_r   = (const float*)d_in[16];
    const float* b1_r   = (const float*)d_in[17];
    const float* W2_r   = (const float*)d_in[18];
    const float* b2_r   = (const float*)d_in[19];
    const float* Wg1    = (const float*)d_in[20];
    const float* bg1    = (const float*)d_in[21];
    const float* Wg2    = (const float*)d_in[22];
    const float* bg2    = (const float*)d_in[23];
    const float* Wp1    = (const float*)d_in[24];
    const float* bp1    = (const float*)d_in[25];
    const float* Wp2    = (const float*)d_in[26];
    const float* bp2    = (const float*)d_in[27];
    float* out = (float*)d_out;

    const int* srcArr = eidx;
    const int* dstArr = eidx + NE;

    // ---- workspace (bump allocator, 256B aligned) ----
    char* w = (char*)d_ws;
    size_t off = 0;
    auto alloc = [&](size_t bytes)->char*{ char* p = w + off; off += (bytes + 255) & ~(size_t)255; return p; };
    bf16* xfeat = (bf16*)alloc((size_t)NN*SEM*2);
    bf16* cur_r = (bf16*)alloc((size_t)NN*SEM*2);
    bf16* cur_g = (bf16*)alloc((size_t)NN*SEM*2);
    bf16* apx   = (bf16*)alloc((size_t)NN*SEM*2);     // rationale-side agg out
    bf16* apx2  = (bf16*)alloc((size_t)NN*SEM*2);     // encoder-side agg out
    char* midc  = alloc((size_t)NN*SHID*2);           // mid_r; reused after trunk:
    bf16* mid_r = (bf16*)midc;
    bf16* Pbuf   = (bf16*)(midc + 12*1024*1024);
    bf16* hidP   = (bf16*)(midc + 20*1024*1024);
    bf16* mid_g = (bf16*)alloc((size_t)NN*SHID*2);
    bf16* wt1g  = (bf16*)alloc((size_t)5*HID*SEM*2);
    bf16* wt2g  = (bf16*)alloc((size_t)5*EMB*SHID*2);
    bf16* wt1r  = (bf16*)alloc((size_t)2*HID*SEM*2);
    bf16* wt2r  = (bf16*)alloc((size_t)2*EMB*SHID*2);
    bf16* wtg1  = (bf16*)alloc((size_t)HID*SEM*2);
    bf16* wtp1  = (bf16*)alloc((size_t)HID*SEM*2);
    float4* epack = (float4*)alloc((size_t)NE*16);
    float* gate  = (float*)alloc((size_t)NN*4);
    float* glogit= (float*)alloc((size_t)NN*2*4);
    float* hr    = (float*)alloc((size_t)NG*EMB*4);
    float* henv  = (float*)alloc((size_t)NG*EMB*4);
    bf16* hrb    = (bf16*)alloc((size_t)NG*SEM*2);
    bf16* henvb  = (bf16*)alloc((size_t)NG*SEM*2);
    float* rnum  = (float*)alloc(NG*4);
    float* cntf  = (float*)alloc(NG*4);
    float* na    = (float*)alloc(NG*4);
    float* ncv   = (float*)alloc(NG*4);
    float* pos   = (float*)alloc(NG*4);
    float* Ssum  = (float*)alloc(NG*4);
    int* deg     = (int*)alloc((size_t)NN*4);
    int* indptr  = (int*)alloc((size_t)(NN+1)*4);
    int* cursor  = (int*)alloc((size_t)NN*4);
    int* gstart  = (int*)alloc((size_t)(NG+1)*4);
    int* bsum    = (int*)alloc((size_t)NBLK_SCAN*4);
    int* boff    = (int*)alloc((size_t)NBLK_SCAN*4);

    const int NB_NE  = (NE+255)/256;
    const int NB_AG  = (NN*CG+255)/256;
    const int NB_GP  = (NG*SEM+255)/256;

    // ---- stream-ordered zeroing (graph-capture-safe), then batched preamble with hist fused ----
    hipMemsetAsync(deg, 0, (size_t)NN*4, stream);
    hipMemsetAsync(glogit, 0, (size_t)NN*2*4, stream);
    dim3 gwp(19, 19, 118);   // z16+z116..117 = hist; z17 gstart; z<16 transposes; z18..115 encoder
    k_wprep_all<<<gwp, 256, 0, stream>>>(W1_g, W2_g, W1_r, W2_r, Wg1, Wp1,
                                         wt1g, wt2g, wt1r, wt2r, wtg1, wtp1,
                                         deg, batch, gstart, x, W_enc, b_enc, xfeat, dstArr);

    // ---- CSR scan + fused scatter/edge-pack ----
    k_scanA      <<<NBLK_SCAN, 256, 0, stream>>>(deg, bsum);
    k_scanB      <<<1, 128, 0, stream>>>(bsum, boff);
    k_scanC      <<<NBLK_SCAN, 256, 0, stream>>>(deg, boff, indptr, cursor);
    k_scatterprep<<<NB_NE, 256, 0, stream>>>(dstArr, srcArr, eattr, cursor, epack);

    dim3 gm1z((HID+127)/128, (NN+127)/128, 2);   // N=600 pairs: (5,235,2)
    dim3 gm160z(2, (NN+127)/128, 2);             // N=300 BN160 pairs: (2,235,2)
    dim3 gm1((HID+127)/128, (NN+127)/128);       // solo N600
    dim3 gm160(2, (NN+127)/128);                 // solo N300 BN160

    // ---- layer 0 (both stacks): shared-gather dual agg, then paired GEMMs ----
    k_agg4d<<<NB_AG, 256, 0, stream>>>(xfeat, We_r, be_r, We_g, be_g, epack, indptr, apx, apx2);
    k_gemm2z<<<gm1z, 256, 0, stream>>>(apx, apx2, wt1r, wt1g, b1_r, b1_g,
                                       nullptr, nullptr, mid_r, mid_g, NN, HID, SEM, SHID, 1, 1);
    k_gemm160z<<<gm160z, 256, 0, stream>>>(mid_r, mid_g, wt2r, wt2g, b2_r, b2_g,
                                           xfeat, xfeat, cur_r, cur_g, NN, EMB, SHID, SEM, 1, 1);

    // ---- layer 1 (both stacks): dual-SOURCE agg (one epack pass) + paired GEMMs ----
    k_agg4dd<<<NB_AG, 256, 0, stream>>>(cur_r, cur_g, We_r + 3*EMB, be_r + EMB,
                                        We_g + 3*EMB, be_g + EMB, epack, indptr, apx, apx2);
    k_gemm2z<<<gm1z, 256, 0, stream>>>(apx, apx2, wt1r + (size_t)HID*SEM, wt1g + (size_t)HID*SEM,
                                       b1_r + HID, b1_g + HID, nullptr, nullptr, mid_r, mid_g,
                                       NN, HID, SEM, SHID, 1, 1);
    k_gemm160z<<<gm160z, 256, 0, stream>>>(mid_r, mid_g, wt2r + (size_t)EMB*SHID, wt2g + (size_t)EMB*SHID,
                                           b2_r + EMB, b2_g + EMB, cur_r, cur_g, cur_r, cur_g,
                                           NN, EMB, SHID, SEM, 0, 1);   // rationale last layer: no relu

    // ---- encoder layer 2 agg; (gate-gemm -> logits) paired with enc-l2 g1; g2+gatefin fused ----
    k_agg4 <<<NB_AG, 256, 0, stream>>>(cur_g, We_g + 2*3*EMB, be_g + 2*EMB, epack, indptr, apx2);
    k_gatepair<<<2350, 256, 0, stream>>>(cur_r, wtg1, bg1, Wg2, glogit,
                                         apx2, wt1g + (size_t)2*HID*SEM, b1_g + 2*HID, mid_g);
    k_g160gate<<<588, 256, 0, stream>>>(mid_g, wt2g + (size_t)2*EMB*SHID, b2_g + 2*EMB, cur_g, cur_g,
                                        glogit, bg2, gumbel, gate);

    // ---- encoder layers 3,4 (solo, swizzled) ----
    for (int l=3; l<5; l++){
        k_agg4 <<<NB_AG, 256, 0, stream>>>(cur_g, We_g + l*3*EMB, be_g + l*EMB, epack, indptr, apx2);
        k_gemm2<<<gm1, 256, 0, stream>>>(apx2, wt1g + (size_t)l*HID*SEM, b1_g + l*HID, nullptr, mid_g,
                                         NN, HID, SEM, SHID, 1);
        k_gemm160<<<gm160, 256, 0, stream>>>(mid_g, wt2g + (size_t)l*EMB*SHID, b2_g + l*EMB, cur_g, cur_g,
                                             NN, EMB, SHID, SEM, (l<4)?1:0);
    }
    // cur_g now holds h_node (bf16, stride SEM)

    // ---- fused pooling + mean + norms ----
    k_poolmean<<<NG, 320, 0, stream>>>(cur_g, gate, gstart, hr, henv, hrb, henvb, Pbuf,
                                       na, ncv, pos, rnum, cntf, Ssum);
    k_pbuild2 <<<NB_GP, 256, 0, stream>>>(hr, henv, perm, Pbuf);
    // ---- contrastive sim rowsums + head GEMM in one fat dispatch ----
    dim3 gsh(12, 24, 2);
    k_simhead<<<gsh, 256, 0, stream>>>(hrb, henvb, na, ncv, Ssum, Pbuf, wtp1, bp1, hidP);
    // ---- pred + loss fused ----
    k_predloss<<<751, 256, 0, stream>>>(hidP, Wp2, bp2, cntf, rnum, pos, Ssum, out);
}